// Round 1
// baseline (1473.440 us; speedup 1.0000x reference)
//
#include <hip/hip_runtime.h>
#include <hip/hip_bf16.h>
#include <math.h>

#define NN 20000
#define EE 320000
#define MM 3
#define FW 256        // NH*HID = NHO*OUT = 256
#define SAH 128
#define NB 79         // ceil(NN/256)

static __device__ __forceinline__ float lrelu(float x){ return x > 0.f ? x : 0.2f*x; }

// ---------------- CSR build ----------------
__global__ __launch_bounds__(256) void hist_kernel(const int* __restrict__ edges, int* __restrict__ cnt) {
    int idx = blockIdx.x*256 + threadIdx.x;
    if (idx >= MM*EE) return;
    int m = idx / EE, e = idx - m*EE;
    int dst = edges[(m*2+1)*EE + e];
    atomicAdd(&cnt[m*NN + dst], 1);
}

__global__ __launch_bounds__(256) void scanA_kernel(const int* __restrict__ cnt, int* __restrict__ rowptr, int* __restrict__ bsum) {
    int m = blockIdx.y;
    int i = blockIdx.x*256 + threadIdx.x;
    int v = (i < NN) ? cnt[m*NN + i] : 0;
    int lane = threadIdx.x & 63;
    int val = v;
    #pragma unroll
    for (int o = 1; o < 64; o <<= 1) { int t = __shfl_up(val, o); if (lane >= o) val += t; }
    __shared__ int ws[4];
    int w = threadIdx.x >> 6;
    if (lane == 63) ws[w] = val;
    __syncthreads();
    #pragma unroll
    for (int j = 0; j < 3; ++j) if (j < w) val += ws[j];
    if (i < NN) rowptr[m*(NN+1) + 1 + i] = val;
    if (threadIdx.x == 255) bsum[m*NB + blockIdx.x] = val;
}

__global__ __launch_bounds__(128) void scanB_kernel(const int* __restrict__ bsum, int* __restrict__ boff) {
    __shared__ int s[128];
    int t = threadIdx.x;
    for (int m = 0; m < MM; ++m) {
        int v = (t < NB) ? bsum[m*NB + t] : 0;
        s[t] = v; __syncthreads();
        for (int o = 1; o < 128; o <<= 1) {
            int x = (t >= o) ? s[t - o] : 0;
            __syncthreads();
            s[t] += x;
            __syncthreads();
        }
        if (t < NB) boff[m*NB + t] = s[t] - v;   // exclusive
        __syncthreads();
    }
}

__global__ __launch_bounds__(256) void scanC_kernel(const int* __restrict__ cnt, int* __restrict__ rowptr,
                                                    const int* __restrict__ boff, int* __restrict__ cursor) {
    int m = blockIdx.y;
    int i = blockIdx.x*256 + threadIdx.x;
    if (i >= NN) return;
    int incl = rowptr[m*(NN+1) + 1 + i] + boff[m*NB + blockIdx.x];
    rowptr[m*(NN+1) + 1 + i] = incl;
    cursor[m*NN + i] = incl - cnt[m*NN + i];
    if (i == 0 && blockIdx.x == 0) rowptr[m*(NN+1)] = 0;
}

__global__ __launch_bounds__(256) void scatter_kernel(const int* __restrict__ edges, int* __restrict__ cursor,
                                                      int* __restrict__ csr_src, int* __restrict__ csr_dst) {
    int idx = blockIdx.x*256 + threadIdx.x;
    if (idx >= MM*EE) return;
    int m = idx / EE, e = idx - m*EE;
    int src = edges[m*2*EE + e];
    int dst = edges[(m*2+1)*EE + e];
    int pos = atomicAdd(&cursor[m*NN + dst], 1);
    csr_src[m*EE + pos] = src;
    csr_dst[m*EE + pos] = dst;
}

// ---------------- GEMM (C = A@B) + el/er epilogue ----------------
// A:[Mrows,256] B:[256,256] C:[Mrows,256]; attl/attr flat [H*D]=[256]
template<int H>
__global__ __launch_bounds__(256) void gemm_attn_kernel(const float* __restrict__ A, const float* __restrict__ B,
                                                        const float* __restrict__ attl, const float* __restrict__ attr,
                                                        float* __restrict__ C, float* __restrict__ el,
                                                        float* __restrict__ er, int Mrows) {
    __shared__ float As[16][68];
    __shared__ float Bs[16][68];
    int tid = threadIdx.x;
    int tx = tid & 15, ty = tid >> 4;
    int row0 = blockIdx.x*64, col0 = blockIdx.y*64;
    float c[4][4] = {};
    int arow = row0 + (tid >> 2);
    int arl  = tid >> 2;
    int ak   = (tid & 3) * 4;
    int bkr  = tid >> 4, bcc = (tid & 15) * 4;

    for (int k0 = 0; k0 < 256; k0 += 16) {
        float4 av = make_float4(0.f,0.f,0.f,0.f);
        if (arow < Mrows) av = *(const float4*)&A[(size_t)arow*256 + k0 + ak];
        As[ak+0][arl] = av.x; As[ak+1][arl] = av.y; As[ak+2][arl] = av.z; As[ak+3][arl] = av.w;
        float4 bv = *(const float4*)&B[(size_t)(k0 + bkr)*256 + col0 + bcc];
        *(float4*)&Bs[bkr][bcc] = bv;
        __syncthreads();
        #pragma unroll
        for (int k = 0; k < 16; ++k) {
            float4 a = *(float4*)&As[k][ty*4];
            float4 b = *(float4*)&Bs[k][tx*4];
            c[0][0] += a.x*b.x; c[0][1] += a.x*b.y; c[0][2] += a.x*b.z; c[0][3] += a.x*b.w;
            c[1][0] += a.y*b.x; c[1][1] += a.y*b.y; c[1][2] += a.y*b.z; c[1][3] += a.y*b.w;
            c[2][0] += a.z*b.x; c[2][1] += a.z*b.y; c[2][2] += a.z*b.z; c[2][3] += a.z*b.w;
            c[3][0] += a.w*b.x; c[3][1] += a.w*b.y; c[3][2] += a.w*b.z; c[3][3] += a.w*b.w;
        }
        __syncthreads();
    }

    float alv[4], arv[4];
    #pragma unroll
    for (int j = 0; j < 4; ++j) { alv[j] = attl[col0 + tx*4 + j]; arv[j] = attr[col0 + tx*4 + j]; }
    int h = (H == 4) ? (int)blockIdx.y : 0;
    #pragma unroll
    for (int i = 0; i < 4; ++i) {
        int r = row0 + ty*4 + i;
        float pel = c[i][0]*alv[0] + c[i][1]*alv[1] + c[i][2]*alv[2] + c[i][3]*alv[3];
        float per = c[i][0]*arv[0] + c[i][1]*arv[1] + c[i][2]*arv[2] + c[i][3]*arv[3];
        #pragma unroll
        for (int o = 1; o < 16; o <<= 1) { pel += __shfl_xor(pel, o); per += __shfl_xor(per, o); }
        if (r < Mrows) {
            *(float4*)&C[(size_t)r*256 + col0 + tx*4] = make_float4(c[i][0], c[i][1], c[i][2], c[i][3]);
            if (tx == 0) { atomicAdd(&el[r*H + h], pel); atomicAdd(&er[r*H + h], per); }
        }
    }
}

// ---------------- edge coefficients ee = exp(leakyrelu(el[src]+er[dst])) ----------------
template<int H>
__global__ __launch_bounds__(256) void edge_ee_kernel(const int* __restrict__ csr_src, const int* __restrict__ csr_dst,
                                                      const float* __restrict__ el, const float* __restrict__ er,
                                                      float* __restrict__ ee) {
    int idx = blockIdx.x*256 + threadIdx.x;
    if (idx >= MM*EE) return;
    int src = csr_src[idx], dst = csr_dst[idx];
    if (H == 4) {
        float4 l = *(const float4*)&el[src*4];
        float4 r = *(const float4*)&er[dst*4];
        float4 s;
        s.x = expf(lrelu(l.x + r.x));
        s.y = expf(lrelu(l.y + r.y));
        s.z = expf(lrelu(l.z + r.z));
        s.w = expf(lrelu(l.w + r.w));
        *(float4*)&ee[(size_t)idx*4] = s;
    } else {
        ee[idx] = expf(lrelu(el[src] + er[dst]));
    }
}

// ---------------- per-dst aggregation: z[n,m,:] = (sum ee*feat[src]) / (sum ee) ----------------
template<int H, bool RELU>
__global__ __launch_bounds__(256) void agg_kernel(const float* __restrict__ feat, const float* __restrict__ ee,
                                                  const int* __restrict__ rowptr, const int* __restrict__ csr_src,
                                                  float* __restrict__ z) {
    int n = blockIdx.x, m = blockIdx.y, tid = threadIdx.x;
    int h = (H == 4) ? (tid >> 6) : 0;
    int beg = rowptr[m*(NN+1) + n], end = rowptr[m*(NN+1) + n + 1];
    float acc = 0.f, den = 0.f;
    for (int e = beg; e < end; ++e) {
        int src = csr_src[m*EE + e];
        float w = (H == 4) ? ee[((size_t)(m*EE + e))*4 + h] : ee[m*EE + e];
        den += w;
        acc += w * feat[(size_t)src*256 + tid];
    }
    float o = acc / (den + 1e-9f);
    if (RELU) o = fmaxf(o, 0.f);
    z[((size_t)n*MM + m)*256 + tid] = o;
}

// ---------------- semantic attention: wsum[m] += sum_n tanh(z@W+b)·v ----------------
__global__ __launch_bounds__(256) void semw_kernel(const float* __restrict__ Z, const float* __restrict__ W,
                                                   const float* __restrict__ bias, const float* __restrict__ v,
                                                   float* __restrict__ wsum) {
    __shared__ float As[16][68];
    __shared__ float Bs[16][132];
    int tid = threadIdx.x;
    int tx = tid & 31, ty = tid >> 5;   // 32 x 8
    int row0 = blockIdx.x * 64;
    float c[8][4] = {};
    int arl = tid >> 2, arow = row0 + arl, ak = (tid & 3)*4;
    int bkr = tid >> 4, bcc = (tid & 15) * 8;

    for (int k0 = 0; k0 < 256; k0 += 16) {
        float4 av = make_float4(0.f,0.f,0.f,0.f);
        if (arow < NN*MM) av = *(const float4*)&Z[(size_t)arow*256 + k0 + ak];
        As[ak+0][arl] = av.x; As[ak+1][arl] = av.y; As[ak+2][arl] = av.z; As[ak+3][arl] = av.w;
        float4 b0 = *(const float4*)&W[(size_t)(k0 + bkr)*SAH + bcc];
        float4 b1 = *(const float4*)&W[(size_t)(k0 + bkr)*SAH + bcc + 4];
        *(float4*)&Bs[bkr][bcc]     = b0;
        *(float4*)&Bs[bkr][bcc + 4] = b1;
        __syncthreads();
        #pragma unroll
        for (int k = 0; k < 16; ++k) {
            float4 a0 = *(float4*)&As[k][ty*8];
            float4 a1 = *(float4*)&As[k][ty*8 + 4];
            float4 b  = *(float4*)&Bs[k][tx*4];
            float aa[8] = {a0.x,a0.y,a0.z,a0.w,a1.x,a1.y,a1.z,a1.w};
            #pragma unroll
            for (int i = 0; i < 8; ++i) {
                c[i][0] += aa[i]*b.x; c[i][1] += aa[i]*b.y; c[i][2] += aa[i]*b.z; c[i][3] += aa[i]*b.w;
            }
        }
        __syncthreads();
    }

    float bb[4], vv[4];
    #pragma unroll
    for (int j = 0; j < 4; ++j) { bb[j] = bias[tx*4 + j]; vv[j] = v[tx*4 + j]; }
    #pragma unroll
    for (int i = 0; i < 8; ++i) {
        int row = row0 + ty*8 + i;
        float p = tanhf(c[i][0] + bb[0]) * vv[0] + tanhf(c[i][1] + bb[1]) * vv[1]
                + tanhf(c[i][2] + bb[2]) * vv[2] + tanhf(c[i][3] + bb[3]) * vv[3];
        #pragma unroll
        for (int o = 1; o < 32; o <<= 1) p += __shfl_xor(p, o);
        if (tx == 0 && row < NN*MM) atomicAdd(&wsum[row % MM], p);
    }
}

__global__ void beta_kernel(const float* __restrict__ wsum, float* __restrict__ beta, float* att_out) {
    if (threadIdx.x == 0 && blockIdx.x == 0) {
        float w0 = wsum[0] / (float)NN, w1 = wsum[1] / (float)NN, w2 = wsum[2] / (float)NN;
        float mx = fmaxf(w0, fmaxf(w1, w2));
        float e0 = expf(w0 - mx), e1 = expf(w1 - mx), e2 = expf(w2 - mx);
        float s = e0 + e1 + e2;
        beta[0] = e0 / s; beta[1] = e1 / s; beta[2] = e2 / s;
        if (att_out) { att_out[0] = e0/s; att_out[1] = e1/s; att_out[2] = e2/s; }
    }
}

__global__ __launch_bounds__(256) void combine_kernel(const float* __restrict__ z, const float* __restrict__ beta,
                                                      float* __restrict__ out) {
    int n = blockIdx.x, d = threadIdx.x;
    float b0 = beta[0], b1 = beta[1], b2 = beta[2];
    size_t base = (size_t)n*MM*256 + d;
    out[(size_t)n*256 + d] = b0*z[base] + b1*z[base + 256] + b2*z[base + 512];
}

extern "C" void kernel_launch(void* const* d_in, const int* in_sizes, int n_in,
                              void* d_out, int out_size, void* d_ws, size_t ws_size,
                              hipStream_t stream) {
    const float* x    = (const float*)d_in[0];
    const int*   edges= (const int*)  d_in[1];
    const float* W1   = (const float*)d_in[2];
    const float* al1  = (const float*)d_in[3];
    const float* ar1  = (const float*)d_in[4];
    const float* saW1 = (const float*)d_in[5];
    const float* sab1 = (const float*)d_in[6];
    const float* sav1 = (const float*)d_in[7];
    const float* W2   = (const float*)d_in[8];
    const float* al2  = (const float*)d_in[9];
    const float* ar2  = (const float*)d_in[10];
    const float* saW2 = (const float*)d_in[11];
    const float* sab2 = (const float*)d_in[12];
    const float* sav2 = (const float*)d_in[13];
    float* out = (float*)d_out;

    char* ws = (char*)d_ws;
    size_t off = 0;
    auto alloc = [&](size_t bytes) { void* p = ws + off; off += (bytes + 255) & ~(size_t)255; return p; };
    float* feat   = (float*)alloc((size_t)NN*256*4);
    float* z      = (float*)alloc((size_t)NN*MM*256*4);
    float* ee     = (float*)alloc((size_t)MM*EE*4*4);
    float* el     = (float*)alloc(NN*4*4);
    float* er     = (float*)alloc(NN*4*4);
    float* wsum   = (float*)alloc(256);
    float* beta   = (float*)alloc(256);
    int*   cnt    = (int*)alloc(MM*NN*4);
    int*   cursor = (int*)alloc(MM*NN*4);
    int*   rowptr = (int*)alloc(MM*(NN+1)*4);
    int*   csr_s  = (int*)alloc((size_t)MM*EE*4);
    int*   csr_d  = (int*)alloc((size_t)MM*EE*4);
    int*   bsum   = (int*)alloc(MM*NB*4);
    int*   boff   = (int*)alloc(MM*NB*4);
    float* h = out;  // reuse d_out as layer-1 output buffer (fully overwritten at the end)

    int egrid = (MM*EE + 255)/256;
    dim3 sg(NB, MM);

    // CSR build (shared by both layers)
    hipMemsetAsync(cnt, 0, MM*NN*4, stream);
    hist_kernel<<<egrid, 256, 0, stream>>>(edges, cnt);
    scanA_kernel<<<sg, 256, 0, stream>>>(cnt, rowptr, bsum);
    scanB_kernel<<<1, 128, 0, stream>>>(bsum, boff);
    scanC_kernel<<<sg, 256, 0, stream>>>(cnt, rowptr, boff, cursor);
    scatter_kernel<<<egrid, 256, 0, stream>>>(edges, cursor, csr_s, csr_d);

    // ---- layer 1 ----
    hipMemsetAsync(el, 0, NN*4*4, stream);
    hipMemsetAsync(er, 0, NN*4*4, stream);
    gemm_attn_kernel<4><<<dim3(313, 4), 256, 0, stream>>>(x, W1, al1, ar1, feat, el, er, NN);
    edge_ee_kernel<4><<<egrid, 256, 0, stream>>>(csr_s, csr_d, el, er, ee);
    agg_kernel<4, true><<<dim3(NN, MM), 256, 0, stream>>>(feat, ee, rowptr, csr_s, z);
    hipMemsetAsync(wsum, 0, 16, stream);
    semw_kernel<<<938, 256, 0, stream>>>(z, saW1, sab1, sav1, wsum);
    beta_kernel<<<1, 64, 0, stream>>>(wsum, beta, nullptr);
    combine_kernel<<<NN, 256, 0, stream>>>(z, beta, h);

    // ---- layer 2 ----
    hipMemsetAsync(el, 0, NN*4, stream);
    hipMemsetAsync(er, 0, NN*4, stream);
    gemm_attn_kernel<1><<<dim3(313, 4), 256, 0, stream>>>(h, W2, al2, ar2, feat, el, er, NN);
    edge_ee_kernel<1><<<egrid, 256, 0, stream>>>(csr_s, csr_d, el, er, ee);
    agg_kernel<1, false><<<dim3(NN, MM), 256, 0, stream>>>(feat, ee, rowptr, csr_s, z);
    hipMemsetAsync(wsum, 0, 16, stream);
    semw_kernel<<<938, 256, 0, stream>>>(z, saW2, sab2, sav2, wsum);
    beta_kernel<<<1, 64, 0, stream>>>(wsum, beta, out + (size_t)NN*256);
    combine_kernel<<<NN, 256, 0, stream>>>(z, beta, out);
}

// Round 2
// 773.050 us; speedup vs baseline: 1.9060x; 1.9060x over previous
//
#include <hip/hip_runtime.h>
#include <hip/hip_bf16.h>
#include <math.h>

#define NN 20000
#define EE 320000
#define MM 3
#define FW 256        // NH*HID = NHO*OUT = 256
#define SAH 128
#define NB 79         // ceil(NN/256)

static __device__ __forceinline__ float lrelu(float x){ return x > 0.f ? x : 0.2f*x; }

// ---------------- CSR build ----------------
__global__ __launch_bounds__(256) void hist_kernel(const int* __restrict__ edges, int* __restrict__ cnt) {
    int idx = blockIdx.x*256 + threadIdx.x;
    if (idx >= MM*EE) return;
    int m = idx / EE, e = idx - m*EE;
    int dst = edges[(m*2+1)*EE + e];
    atomicAdd(&cnt[m*NN + dst], 1);
}

__global__ __launch_bounds__(256) void scanA_kernel(const int* __restrict__ cnt, int* __restrict__ rowptr, int* __restrict__ bsum) {
    int m = blockIdx.y;
    int i = blockIdx.x*256 + threadIdx.x;
    int v = (i < NN) ? cnt[m*NN + i] : 0;
    int lane = threadIdx.x & 63;
    int val = v;
    #pragma unroll
    for (int o = 1; o < 64; o <<= 1) { int t = __shfl_up(val, o); if (lane >= o) val += t; }
    __shared__ int ws[4];
    int w = threadIdx.x >> 6;
    if (lane == 63) ws[w] = val;
    __syncthreads();
    #pragma unroll
    for (int j = 0; j < 3; ++j) if (j < w) val += ws[j];
    if (i < NN) rowptr[m*(NN+1) + 1 + i] = val;
    if (threadIdx.x == 255) bsum[m*NB + blockIdx.x] = val;
}

__global__ __launch_bounds__(128) void scanB_kernel(const int* __restrict__ bsum, int* __restrict__ boff) {
    __shared__ int s[128];
    int t = threadIdx.x;
    for (int m = 0; m < MM; ++m) {
        int v = (t < NB) ? bsum[m*NB + t] : 0;
        s[t] = v; __syncthreads();
        for (int o = 1; o < 128; o <<= 1) {
            int x = (t >= o) ? s[t - o] : 0;
            __syncthreads();
            s[t] += x;
            __syncthreads();
        }
        if (t < NB) boff[m*NB + t] = s[t] - v;   // exclusive
        __syncthreads();
    }
}

__global__ __launch_bounds__(256) void scanC_kernel(const int* __restrict__ cnt, int* __restrict__ rowptr,
                                                    const int* __restrict__ boff, int* __restrict__ cursor) {
    int m = blockIdx.y;
    int i = blockIdx.x*256 + threadIdx.x;
    if (i >= NN) return;
    int incl = rowptr[m*(NN+1) + 1 + i] + boff[m*NB + blockIdx.x];
    rowptr[m*(NN+1) + 1 + i] = incl;
    cursor[m*NN + i] = incl - cnt[m*NN + i];
    if (i == 0 && blockIdx.x == 0) rowptr[m*(NN+1)] = 0;
}

__global__ __launch_bounds__(256) void scatter_kernel(const int* __restrict__ edges, int* __restrict__ cursor,
                                                      int* __restrict__ csr_src, int* __restrict__ csr_dst) {
    int idx = blockIdx.x*256 + threadIdx.x;
    if (idx >= MM*EE) return;
    int m = idx / EE, e = idx - m*EE;
    int src = edges[m*2*EE + e];
    int dst = edges[(m*2+1)*EE + e];
    int pos = atomicAdd(&cursor[m*NN + dst], 1);
    csr_src[m*EE + pos] = src;
    csr_dst[m*EE + pos] = dst;
}

// ---------------- GEMM (C = A@B) + el/er epilogue ----------------
// A:[Mrows,256] B:[256,256] C:[Mrows,256]; attl/attr flat [H*D]=[256]
template<int H>
__global__ __launch_bounds__(256) void gemm_attn_kernel(const float* __restrict__ A, const float* __restrict__ B,
                                                        const float* __restrict__ attl, const float* __restrict__ attr,
                                                        float* __restrict__ C, float* __restrict__ el,
                                                        float* __restrict__ er, int Mrows) {
    __shared__ float As[16][68];
    __shared__ float Bs[16][68];
    int tid = threadIdx.x;
    int tx = tid & 15, ty = tid >> 4;
    int row0 = blockIdx.x*64, col0 = blockIdx.y*64;
    float c[4][4] = {};
    int arow = row0 + (tid >> 2);
    int arl  = tid >> 2;
    int ak   = (tid & 3) * 4;
    int bkr  = tid >> 4, bcc = (tid & 15) * 4;

    for (int k0 = 0; k0 < 256; k0 += 16) {
        float4 av = make_float4(0.f,0.f,0.f,0.f);
        if (arow < Mrows) av = *(const float4*)&A[(size_t)arow*256 + k0 + ak];
        As[ak+0][arl] = av.x; As[ak+1][arl] = av.y; As[ak+2][arl] = av.z; As[ak+3][arl] = av.w;
        float4 bv = *(const float4*)&B[(size_t)(k0 + bkr)*256 + col0 + bcc];
        *(float4*)&Bs[bkr][bcc] = bv;
        __syncthreads();
        #pragma unroll
        for (int k = 0; k < 16; ++k) {
            float4 a = *(float4*)&As[k][ty*4];
            float4 b = *(float4*)&Bs[k][tx*4];
            c[0][0] += a.x*b.x; c[0][1] += a.x*b.y; c[0][2] += a.x*b.z; c[0][3] += a.x*b.w;
            c[1][0] += a.y*b.x; c[1][1] += a.y*b.y; c[1][2] += a.y*b.z; c[1][3] += a.y*b.w;
            c[2][0] += a.z*b.x; c[2][1] += a.z*b.y; c[2][2] += a.z*b.z; c[2][3] += a.z*b.w;
            c[3][0] += a.w*b.x; c[3][1] += a.w*b.y; c[3][2] += a.w*b.z; c[3][3] += a.w*b.w;
        }
        __syncthreads();
    }

    float alv[4], arv[4];
    #pragma unroll
    for (int j = 0; j < 4; ++j) { alv[j] = attl[col0 + tx*4 + j]; arv[j] = attr[col0 + tx*4 + j]; }
    int h = (H == 4) ? (int)blockIdx.y : 0;
    #pragma unroll
    for (int i = 0; i < 4; ++i) {
        int r = row0 + ty*4 + i;
        float pel = c[i][0]*alv[0] + c[i][1]*alv[1] + c[i][2]*alv[2] + c[i][3]*alv[3];
        float per = c[i][0]*arv[0] + c[i][1]*arv[1] + c[i][2]*arv[2] + c[i][3]*arv[3];
        #pragma unroll
        for (int o = 1; o < 16; o <<= 1) { pel += __shfl_xor(pel, o); per += __shfl_xor(per, o); }
        if (r < Mrows) {
            *(float4*)&C[(size_t)r*256 + col0 + tx*4] = make_float4(c[i][0], c[i][1], c[i][2], c[i][3]);
            if (tx == 0) { atomicAdd(&el[r*H + h], pel); atomicAdd(&er[r*H + h], per); }
        }
    }
}

// ---------------- edge coefficients ee = exp(leakyrelu(el[src]+er[dst])) ----------------
template<int H>
__global__ __launch_bounds__(256) void edge_ee_kernel(const int* __restrict__ csr_src, const int* __restrict__ csr_dst,
                                                      const float* __restrict__ el, const float* __restrict__ er,
                                                      float* __restrict__ ee) {
    int idx = blockIdx.x*256 + threadIdx.x;
    if (idx >= MM*EE) return;
    int src = csr_src[idx], dst = csr_dst[idx];
    if (H == 4) {
        float4 l = *(const float4*)&el[src*4];
        float4 r = *(const float4*)&er[dst*4];
        float4 s;
        s.x = expf(lrelu(l.x + r.x));
        s.y = expf(lrelu(l.y + r.y));
        s.z = expf(lrelu(l.z + r.z));
        s.w = expf(lrelu(l.w + r.w));
        *(float4*)&ee[(size_t)idx*4] = s;
    } else {
        ee[idx] = expf(lrelu(el[src] + er[dst]));
    }
}

// ---------------- per-dst aggregation: z[n,m,:] = (sum ee*feat[src]) / (sum ee) ----------------
template<int H, bool RELU>
__global__ __launch_bounds__(256) void agg_kernel(const float* __restrict__ feat, const float* __restrict__ ee,
                                                  const int* __restrict__ rowptr, const int* __restrict__ csr_src,
                                                  float* __restrict__ z) {
    int n = blockIdx.x, m = blockIdx.y, tid = threadIdx.x;
    int h = (H == 4) ? (tid >> 6) : 0;
    int beg = rowptr[m*(NN+1) + n], end = rowptr[m*(NN+1) + n + 1];
    float acc = 0.f, den = 0.f;
    for (int e = beg; e < end; ++e) {
        int src = csr_src[m*EE + e];
        float w = (H == 4) ? ee[((size_t)(m*EE + e))*4 + h] : ee[m*EE + e];
        den += w;
        acc += w * feat[(size_t)src*256 + tid];
    }
    float o = acc / (den + 1e-9f);
    if (RELU) o = fmaxf(o, 0.f);
    z[((size_t)n*MM + m)*256 + tid] = o;
}

// ---------------- semantic attention: wsum[m] += sum_n tanh(z@W+b)·v ----------------
__global__ __launch_bounds__(256) void semw_kernel(const float* __restrict__ Z, const float* __restrict__ W,
                                                   const float* __restrict__ bias, const float* __restrict__ v,
                                                   float* __restrict__ wsum) {
    __shared__ float As[16][68];
    __shared__ float Bs[16][132];
    int tid = threadIdx.x;
    int tx = tid & 31, ty = tid >> 5;   // 32 x 8
    int row0 = blockIdx.x * 64;
    float c[8][4] = {};
    int arl = tid >> 2, arow = row0 + arl, ak = (tid & 3)*4;
    int bkr = tid >> 4, bcc = (tid & 15) * 8;

    for (int k0 = 0; k0 < 256; k0 += 16) {
        float4 av = make_float4(0.f,0.f,0.f,0.f);
        if (arow < NN*MM) av = *(const float4*)&Z[(size_t)arow*256 + k0 + ak];
        As[ak+0][arl] = av.x; As[ak+1][arl] = av.y; As[ak+2][arl] = av.z; As[ak+3][arl] = av.w;
        float4 b0 = *(const float4*)&W[(size_t)(k0 + bkr)*SAH + bcc];
        float4 b1 = *(const float4*)&W[(size_t)(k0 + bkr)*SAH + bcc + 4];
        *(float4*)&Bs[bkr][bcc]     = b0;
        *(float4*)&Bs[bkr][bcc + 4] = b1;
        __syncthreads();
        #pragma unroll
        for (int k = 0; k < 16; ++k) {
            float4 a0 = *(float4*)&As[k][ty*8];
            float4 a1 = *(float4*)&As[k][ty*8 + 4];
            float4 b  = *(float4*)&Bs[k][tx*4];
            float aa[8] = {a0.x,a0.y,a0.z,a0.w,a1.x,a1.y,a1.z,a1.w};
            #pragma unroll
            for (int i = 0; i < 8; ++i) {
                c[i][0] += aa[i]*b.x; c[i][1] += aa[i]*b.y; c[i][2] += aa[i]*b.z; c[i][3] += aa[i]*b.w;
            }
        }
        __syncthreads();
    }

    float bb[4], vv[4];
    #pragma unroll
    for (int j = 0; j < 4; ++j) { bb[j] = bias[tx*4 + j]; vv[j] = v[tx*4 + j]; }

    // Two-level reduction: per-thread -> per-wave (shuffle) -> per-block (LDS)
    // -> 3 global atomics per block. Avoids 60k same-address atomics.
    float loc[3] = {0.f, 0.f, 0.f};
    #pragma unroll
    for (int i = 0; i < 8; ++i) {
        int row = row0 + ty*8 + i;
        float p = tanhf(c[i][0] + bb[0]) * vv[0] + tanhf(c[i][1] + bb[1]) * vv[1]
                + tanhf(c[i][2] + bb[2]) * vv[2] + tanhf(c[i][3] + bb[3]) * vv[3];
        #pragma unroll
        for (int o = 1; o < 32; o <<= 1) p += __shfl_xor(p, o);
        if (tx == 0 && row < NN*MM) loc[row % MM] += p;
    }
    __shared__ float red[8][3];
    if (tx == 0) { red[ty][0] = loc[0]; red[ty][1] = loc[1]; red[ty][2] = loc[2]; }
    __syncthreads();
    if (tid < MM) {
        float s = 0.f;
        #pragma unroll
        for (int j = 0; j < 8; ++j) s += red[j][tid];
        atomicAdd(&wsum[tid], s);
    }
}

__global__ void beta_kernel(const float* __restrict__ wsum, float* __restrict__ beta, float* att_out) {
    if (threadIdx.x == 0 && blockIdx.x == 0) {
        float w0 = wsum[0] / (float)NN, w1 = wsum[1] / (float)NN, w2 = wsum[2] / (float)NN;
        float mx = fmaxf(w0, fmaxf(w1, w2));
        float e0 = expf(w0 - mx), e1 = expf(w1 - mx), e2 = expf(w2 - mx);
        float s = e0 + e1 + e2;
        beta[0] = e0 / s; beta[1] = e1 / s; beta[2] = e2 / s;
        if (att_out) { att_out[0] = e0/s; att_out[1] = e1/s; att_out[2] = e2/s; }
    }
}

__global__ __launch_bounds__(256) void combine_kernel(const float* __restrict__ z, const float* __restrict__ beta,
                                                      float* __restrict__ out) {
    int n = blockIdx.x, d = threadIdx.x;
    float b0 = beta[0], b1 = beta[1], b2 = beta[2];
    size_t base = (size_t)n*MM*256 + d;
    out[(size_t)n*256 + d] = b0*z[base] + b1*z[base + 256] + b2*z[base + 512];
}

extern "C" void kernel_launch(void* const* d_in, const int* in_sizes, int n_in,
                              void* d_out, int out_size, void* d_ws, size_t ws_size,
                              hipStream_t stream) {
    const float* x    = (const float*)d_in[0];
    const int*   edges= (const int*)  d_in[1];
    const float* W1   = (const float*)d_in[2];
    const float* al1  = (const float*)d_in[3];
    const float* ar1  = (const float*)d_in[4];
    const float* saW1 = (const float*)d_in[5];
    const float* sab1 = (const float*)d_in[6];
    const float* sav1 = (const float*)d_in[7];
    const float* W2   = (const float*)d_in[8];
    const float* al2  = (const float*)d_in[9];
    const float* ar2  = (const float*)d_in[10];
    const float* saW2 = (const float*)d_in[11];
    const float* sab2 = (const float*)d_in[12];
    const float* sav2 = (const float*)d_in[13];
    float* out = (float*)d_out;

    char* ws = (char*)d_ws;
    size_t off = 0;
    auto alloc = [&](size_t bytes) { void* p = ws + off; off += (bytes + 255) & ~(size_t)255; return p; };
    float* feat   = (float*)alloc((size_t)NN*256*4);
    float* z      = (float*)alloc((size_t)NN*MM*256*4);
    float* ee     = (float*)alloc((size_t)MM*EE*4*4);
    float* el     = (float*)alloc(NN*4*4);
    float* er     = (float*)alloc(NN*4*4);
    float* wsum   = (float*)alloc(256);
    float* beta   = (float*)alloc(256);
    int*   cnt    = (int*)alloc(MM*NN*4);
    int*   cursor = (int*)alloc(MM*NN*4);
    int*   rowptr = (int*)alloc(MM*(NN+1)*4);
    int*   csr_s  = (int*)alloc((size_t)MM*EE*4);
    int*   csr_d  = (int*)alloc((size_t)MM*EE*4);
    int*   bsum   = (int*)alloc(MM*NB*4);
    int*   boff   = (int*)alloc(MM*NB*4);
    float* h = out;  // reuse d_out as layer-1 output buffer (fully overwritten at the end)

    int egrid = (MM*EE + 255)/256;
    dim3 sg(NB, MM);

    // CSR build (shared by both layers)
    hipMemsetAsync(cnt, 0, MM*NN*4, stream);
    hist_kernel<<<egrid, 256, 0, stream>>>(edges, cnt);
    scanA_kernel<<<sg, 256, 0, stream>>>(cnt, rowptr, bsum);
    scanB_kernel<<<1, 128, 0, stream>>>(bsum, boff);
    scanC_kernel<<<sg, 256, 0, stream>>>(cnt, rowptr, boff, cursor);
    scatter_kernel<<<egrid, 256, 0, stream>>>(edges, cursor, csr_s, csr_d);

    // ---- layer 1 ----
    hipMemsetAsync(el, 0, NN*4*4, stream);
    hipMemsetAsync(er, 0, NN*4*4, stream);
    gemm_attn_kernel<4><<<dim3(313, 4), 256, 0, stream>>>(x, W1, al1, ar1, feat, el, er, NN);
    edge_ee_kernel<4><<<egrid, 256, 0, stream>>>(csr_s, csr_d, el, er, ee);
    agg_kernel<4, true><<<dim3(NN, MM), 256, 0, stream>>>(feat, ee, rowptr, csr_s, z);
    hipMemsetAsync(wsum, 0, 16, stream);
    semw_kernel<<<938, 256, 0, stream>>>(z, saW1, sab1, sav1, wsum);
    beta_kernel<<<1, 64, 0, stream>>>(wsum, beta, nullptr);
    combine_kernel<<<NN, 256, 0, stream>>>(z, beta, h);

    // ---- layer 2 ----
    hipMemsetAsync(el, 0, NN*4, stream);
    hipMemsetAsync(er, 0, NN*4, stream);
    gemm_attn_kernel<1><<<dim3(313, 4), 256, 0, stream>>>(h, W2, al2, ar2, feat, el, er, NN);
    edge_ee_kernel<1><<<egrid, 256, 0, stream>>>(csr_s, csr_d, el, er, ee);
    agg_kernel<1, false><<<dim3(NN, MM), 256, 0, stream>>>(feat, ee, rowptr, csr_s, z);
    hipMemsetAsync(wsum, 0, 16, stream);
    semw_kernel<<<938, 256, 0, stream>>>(z, saW2, sab2, sav2, wsum);
    beta_kernel<<<1, 64, 0, stream>>>(wsum, beta, out + (size_t)NN*256);
    combine_kernel<<<NN, 256, 0, stream>>>(z, beta, out);
}

// Round 3
// 607.066 us; speedup vs baseline: 2.4271x; 1.2734x over previous
//
#include <hip/hip_runtime.h>
#include <hip/hip_bf16.h>
#include <math.h>

#define NN 20000
#define EE 320000
#define MM 3
#define FW 256        // NH*HID = NHO*OUT = 256
#define SAH 128
#define NB 79         // ceil(NN/256)

static __device__ __forceinline__ float lrelu(float x){ return x > 0.f ? x : 0.2f*x; }

// fp32 -> bf16 round-to-nearest-even (values are finite/small; no NaN handling needed)
static __device__ __forceinline__ unsigned short f2bf(float f) {
    unsigned u = __float_as_uint(f);
    return (unsigned short)((u + 0x7FFFu + ((u >> 16) & 1u)) >> 16);
}
static __device__ __forceinline__ float bf2f(unsigned short b) {
    return __uint_as_float(((unsigned)b) << 16);
}

// ---------------- CSR build ----------------
__global__ __launch_bounds__(256) void hist_kernel(const int* __restrict__ edges, int* __restrict__ cnt) {
    int idx = blockIdx.x*256 + threadIdx.x;
    if (idx >= MM*EE) return;
    int m = idx / EE, e = idx - m*EE;
    int dst = edges[(m*2+1)*EE + e];
    atomicAdd(&cnt[m*NN + dst], 1);
}

__global__ __launch_bounds__(256) void scanA_kernel(const int* __restrict__ cnt, int* __restrict__ rowptr, int* __restrict__ bsum) {
    int m = blockIdx.y;
    int i = blockIdx.x*256 + threadIdx.x;
    int v = (i < NN) ? cnt[m*NN + i] : 0;
    int lane = threadIdx.x & 63;
    int val = v;
    #pragma unroll
    for (int o = 1; o < 64; o <<= 1) { int t = __shfl_up(val, o); if (lane >= o) val += t; }
    __shared__ int ws[4];
    int w = threadIdx.x >> 6;
    if (lane == 63) ws[w] = val;
    __syncthreads();
    #pragma unroll
    for (int j = 0; j < 3; ++j) if (j < w) val += ws[j];
    if (i < NN) rowptr[m*(NN+1) + 1 + i] = val;
    if (threadIdx.x == 255) bsum[m*NB + blockIdx.x] = val;
}

__global__ __launch_bounds__(128) void scanB_kernel(const int* __restrict__ bsum, int* __restrict__ boff) {
    __shared__ int s[128];
    int t = threadIdx.x;
    for (int m = 0; m < MM; ++m) {
        int v = (t < NB) ? bsum[m*NB + t] : 0;
        s[t] = v; __syncthreads();
        for (int o = 1; o < 128; o <<= 1) {
            int x = (t >= o) ? s[t - o] : 0;
            __syncthreads();
            s[t] += x;
            __syncthreads();
        }
        if (t < NB) boff[m*NB + t] = s[t] - v;   // exclusive
        __syncthreads();
    }
}

__global__ __launch_bounds__(256) void scanC_kernel(const int* __restrict__ cnt, int* __restrict__ rowptr,
                                                    const int* __restrict__ boff, int* __restrict__ cursor) {
    int m = blockIdx.y;
    int i = blockIdx.x*256 + threadIdx.x;
    if (i >= NN) return;
    int incl = rowptr[m*(NN+1) + 1 + i] + boff[m*NB + blockIdx.x];
    rowptr[m*(NN+1) + 1 + i] = incl;
    cursor[m*NN + i] = incl - cnt[m*NN + i];
    if (i == 0 && blockIdx.x == 0) rowptr[m*(NN+1)] = 0;
}

__global__ __launch_bounds__(256) void scatter_kernel(const int* __restrict__ edges, int* __restrict__ cursor,
                                                      int* __restrict__ csr_src) {
    int idx = blockIdx.x*256 + threadIdx.x;
    if (idx >= MM*EE) return;
    int m = idx / EE, e = idx - m*EE;
    int src = edges[m*2*EE + e];
    int dst = edges[(m*2+1)*EE + e];
    int pos = atomicAdd(&cursor[m*NN + dst], 1);
    csr_src[m*EE + pos] = src;
}

// ---------------- GEMM (C = A@B) + el/er epilogue; C written as bf16 ----------------
// A:[Mrows,256] B:[256,256] C:[Mrows,256] bf16; attl/attr flat [H*D]=[256]
template<int H>
__global__ __launch_bounds__(256) void gemm_attn_kernel(const float* __restrict__ A, const float* __restrict__ B,
                                                        const float* __restrict__ attl, const float* __restrict__ attr,
                                                        unsigned short* __restrict__ C, float* __restrict__ el,
                                                        float* __restrict__ er, int Mrows) {
    __shared__ float As[16][68];
    __shared__ float Bs[16][68];
    int tid = threadIdx.x;
    int tx = tid & 15, ty = tid >> 4;
    int row0 = blockIdx.x*64, col0 = blockIdx.y*64;
    float c[4][4] = {};
    int arow = row0 + (tid >> 2);
    int arl  = tid >> 2;
    int ak   = (tid & 3) * 4;
    int bkr  = tid >> 4, bcc = (tid & 15) * 4;

    for (int k0 = 0; k0 < 256; k0 += 16) {
        float4 av = make_float4(0.f,0.f,0.f,0.f);
        if (arow < Mrows) av = *(const float4*)&A[(size_t)arow*256 + k0 + ak];
        As[ak+0][arl] = av.x; As[ak+1][arl] = av.y; As[ak+2][arl] = av.z; As[ak+3][arl] = av.w;
        float4 bv = *(const float4*)&B[(size_t)(k0 + bkr)*256 + col0 + bcc];
        *(float4*)&Bs[bkr][bcc] = bv;
        __syncthreads();
        #pragma unroll
        for (int k = 0; k < 16; ++k) {
            float4 a = *(float4*)&As[k][ty*4];
            float4 b = *(float4*)&Bs[k][tx*4];
            c[0][0] += a.x*b.x; c[0][1] += a.x*b.y; c[0][2] += a.x*b.z; c[0][3] += a.x*b.w;
            c[1][0] += a.y*b.x; c[1][1] += a.y*b.y; c[1][2] += a.y*b.z; c[1][3] += a.y*b.w;
            c[2][0] += a.z*b.x; c[2][1] += a.z*b.y; c[2][2] += a.z*b.z; c[2][3] += a.z*b.w;
            c[3][0] += a.w*b.x; c[3][1] += a.w*b.y; c[3][2] += a.w*b.z; c[3][3] += a.w*b.w;
        }
        __syncthreads();
    }

    float alv[4], arv[4];
    #pragma unroll
    for (int j = 0; j < 4; ++j) { alv[j] = attl[col0 + tx*4 + j]; arv[j] = attr[col0 + tx*4 + j]; }
    int h = (H == 4) ? (int)blockIdx.y : 0;
    #pragma unroll
    for (int i = 0; i < 4; ++i) {
        int r = row0 + ty*4 + i;
        float pel = c[i][0]*alv[0] + c[i][1]*alv[1] + c[i][2]*alv[2] + c[i][3]*alv[3];
        float per = c[i][0]*arv[0] + c[i][1]*arv[1] + c[i][2]*arv[2] + c[i][3]*arv[3];
        #pragma unroll
        for (int o = 1; o < 16; o <<= 1) { pel += __shfl_xor(pel, o); per += __shfl_xor(per, o); }
        if (r < Mrows) {
            ushort4 cv;
            cv.x = f2bf(c[i][0]); cv.y = f2bf(c[i][1]); cv.z = f2bf(c[i][2]); cv.w = f2bf(c[i][3]);
            *(ushort4*)&C[(size_t)r*256 + col0 + tx*4] = cv;
            if (tx == 0) { atomicAdd(&el[r*H + h], pel); atomicAdd(&er[r*H + h], per); }
        }
    }
}

// ---------------- per-dst aggregation (fused edge coefficients) ----------------
// z[n,m,:] = (sum_e ee*feat[src_e]) / (sum_e ee),  ee = exp(lrelu(el[src]+er[n]))
// Block = 4 waves x 64 lanes. Wave w takes edges beg+w, beg+w+4, ...
// Lane holds features [lane*4, lane*4+4) (one head group for H=4).
template<int H, bool RELU>
__global__ __launch_bounds__(256) void agg_kernel(const unsigned short* __restrict__ feat,
                                                  const float* __restrict__ el,
                                                  const float* __restrict__ er,
                                                  const int* __restrict__ rowptr,
                                                  const int* __restrict__ csr_src,
                                                  float* __restrict__ z) {
    int n = blockIdx.x, m = blockIdx.y;
    int tid = threadIdx.x;
    int lane = tid & 63, wv = tid >> 6;
    int h = (H == 4) ? (lane >> 4) : 0;
    float ern = (H == 4) ? er[n*4 + h] : er[n];
    int beg = rowptr[m*(NN+1) + n], end = rowptr[m*(NN+1) + n + 1];

    float a0 = 0.f, a1 = 0.f, a2 = 0.f, a3 = 0.f, den = 0.f;
    int e = beg + wv;
    if (e < end) {
        // software prefetch of next edge's index + el so gather addr is ready
        int srcn = csr_src[m*EE + e];
        float eln = (H == 4) ? el[srcn*4 + h] : el[srcn];
        for (;;) {
            int src = srcn; float elv = eln;
            int e2 = e + 4;
            if (e2 < end) {
                srcn = csr_src[m*EE + e2];
                eln = (H == 4) ? el[srcn*4 + h] : el[srcn];
            }
            ushort4 v = *(const ushort4*)(feat + (size_t)src*256 + lane*4);
            float wgt = expf(lrelu(elv + ern));
            den += wgt;
            a0 += wgt * bf2f(v.x);
            a1 += wgt * bf2f(v.y);
            a2 += wgt * bf2f(v.z);
            a3 += wgt * bf2f(v.w);
            e = e2;
            if (e >= end) break;
        }
    }

    __shared__ float part[4][256];
    __shared__ float dpart[4][64];
    *(float4*)&part[wv][lane*4] = make_float4(a0, a1, a2, a3);
    dpart[wv][lane] = den;
    __syncthreads();

    int f = tid;
    float s  = part[0][f] + part[1][f] + part[2][f] + part[3][f];
    int dl = f >> 2;
    float ds = dpart[0][dl] + dpart[1][dl] + dpart[2][dl] + dpart[3][dl];
    float o = s / (ds + 1e-9f);
    if (RELU) o = fmaxf(o, 0.f);
    z[((size_t)n*MM + m)*256 + f] = o;
}

// ---------------- semantic attention: wsum[m] += sum_n tanh(z@W+b)·v ----------------
__global__ __launch_bounds__(256) void semw_kernel(const float* __restrict__ Z, const float* __restrict__ W,
                                                   const float* __restrict__ bias, const float* __restrict__ v,
                                                   float* __restrict__ wsum) {
    __shared__ float As[16][68];
    __shared__ float Bs[16][132];
    int tid = threadIdx.x;
    int tx = tid & 31, ty = tid >> 5;   // 32 x 8
    int row0 = blockIdx.x * 64;
    float c[8][4] = {};
    int arl = tid >> 2, arow = row0 + arl, ak = (tid & 3)*4;
    int bkr = tid >> 4, bcc = (tid & 15) * 8;

    for (int k0 = 0; k0 < 256; k0 += 16) {
        float4 av = make_float4(0.f,0.f,0.f,0.f);
        if (arow < NN*MM) av = *(const float4*)&Z[(size_t)arow*256 + k0 + ak];
        As[ak+0][arl] = av.x; As[ak+1][arl] = av.y; As[ak+2][arl] = av.z; As[ak+3][arl] = av.w;
        float4 b0 = *(const float4*)&W[(size_t)(k0 + bkr)*SAH + bcc];
        float4 b1 = *(const float4*)&W[(size_t)(k0 + bkr)*SAH + bcc + 4];
        *(float4*)&Bs[bkr][bcc]     = b0;
        *(float4*)&Bs[bkr][bcc + 4] = b1;
        __syncthreads();
        #pragma unroll
        for (int k = 0; k < 16; ++k) {
            float4 a0 = *(float4*)&As[k][ty*8];
            float4 a1 = *(float4*)&As[k][ty*8 + 4];
            float4 b  = *(float4*)&Bs[k][tx*4];
            float aa[8] = {a0.x,a0.y,a0.z,a0.w,a1.x,a1.y,a1.z,a1.w};
            #pragma unroll
            for (int i = 0; i < 8; ++i) {
                c[i][0] += aa[i]*b.x; c[i][1] += aa[i]*b.y; c[i][2] += aa[i]*b.z; c[i][3] += aa[i]*b.w;
            }
        }
        __syncthreads();
    }

    float bb[4], vv[4];
    #pragma unroll
    for (int j = 0; j < 4; ++j) { bb[j] = bias[tx*4 + j]; vv[j] = v[tx*4 + j]; }

    // Two-level reduction: per-thread -> per-wave (shuffle) -> per-block (LDS)
    // -> 3 global atomics per block. Avoids 60k same-address atomics.
    float loc[3] = {0.f, 0.f, 0.f};
    #pragma unroll
    for (int i = 0; i < 8; ++i) {
        int row = row0 + ty*8 + i;
        float p = tanhf(c[i][0] + bb[0]) * vv[0] + tanhf(c[i][1] + bb[1]) * vv[1]
                + tanhf(c[i][2] + bb[2]) * vv[2] + tanhf(c[i][3] + bb[3]) * vv[3];
        #pragma unroll
        for (int o = 1; o < 32; o <<= 1) p += __shfl_xor(p, o);
        if (tx == 0 && row < NN*MM) loc[row % MM] += p;
    }
    __shared__ float red[8][3];
    if (tx == 0) { red[ty][0] = loc[0]; red[ty][1] = loc[1]; red[ty][2] = loc[2]; }
    __syncthreads();
    if (tid < MM) {
        float s = 0.f;
        #pragma unroll
        for (int j = 0; j < 8; ++j) s += red[j][tid];
        atomicAdd(&wsum[tid], s);
    }
}

__global__ void beta_kernel(const float* __restrict__ wsum, float* __restrict__ beta, float* att_out) {
    if (threadIdx.x == 0 && blockIdx.x == 0) {
        float w0 = wsum[0] / (float)NN, w1 = wsum[1] / (float)NN, w2 = wsum[2] / (float)NN;
        float mx = fmaxf(w0, fmaxf(w1, w2));
        float e0 = expf(w0 - mx), e1 = expf(w1 - mx), e2 = expf(w2 - mx);
        float s = e0 + e1 + e2;
        beta[0] = e0 / s; beta[1] = e1 / s; beta[2] = e2 / s;
        if (att_out) { att_out[0] = e0/s; att_out[1] = e1/s; att_out[2] = e2/s; }
    }
}

__global__ __launch_bounds__(256) void combine_kernel(const float* __restrict__ z, const float* __restrict__ beta,
                                                      float* __restrict__ out) {
    int n = blockIdx.x, d = threadIdx.x;
    float b0 = beta[0], b1 = beta[1], b2 = beta[2];
    size_t base = (size_t)n*MM*256 + d;
    out[(size_t)n*256 + d] = b0*z[base] + b1*z[base + 256] + b2*z[base + 512];
}

extern "C" void kernel_launch(void* const* d_in, const int* in_sizes, int n_in,
                              void* d_out, int out_size, void* d_ws, size_t ws_size,
                              hipStream_t stream) {
    const float* x    = (const float*)d_in[0];
    const int*   edges= (const int*)  d_in[1];
    const float* W1   = (const float*)d_in[2];
    const float* al1  = (const float*)d_in[3];
    const float* ar1  = (const float*)d_in[4];
    const float* saW1 = (const float*)d_in[5];
    const float* sab1 = (const float*)d_in[6];
    const float* sav1 = (const float*)d_in[7];
    const float* W2   = (const float*)d_in[8];
    const float* al2  = (const float*)d_in[9];
    const float* ar2  = (const float*)d_in[10];
    const float* saW2 = (const float*)d_in[11];
    const float* sab2 = (const float*)d_in[12];
    const float* sav2 = (const float*)d_in[13];
    float* out = (float*)d_out;

    char* ws = (char*)d_ws;
    size_t off = 0;
    auto alloc = [&](size_t bytes) { void* p = ws + off; off += (bytes + 255) & ~(size_t)255; return p; };
    unsigned short* feat = (unsigned short*)alloc((size_t)NN*256*2);   // bf16
    float* z      = (float*)alloc((size_t)NN*MM*256*4);
    float* el     = (float*)alloc(NN*4*4);
    float* er     = (float*)alloc(NN*4*4);
    float* wsum   = (float*)alloc(256);
    float* beta   = (float*)alloc(256);
    int*   cnt    = (int*)alloc(MM*NN*4);
    int*   cursor = (int*)alloc(MM*NN*4);
    int*   rowptr = (int*)alloc(MM*(NN+1)*4);
    int*   csr_s  = (int*)alloc((size_t)MM*EE*4);
    int*   bsum   = (int*)alloc(MM*NB*4);
    int*   boff   = (int*)alloc(MM*NB*4);
    float* h = out;  // reuse d_out as layer-1 output buffer (fully overwritten at the end)

    int egrid = (MM*EE + 255)/256;
    dim3 sg(NB, MM);

    // CSR build (shared by both layers)
    hipMemsetAsync(cnt, 0, MM*NN*4, stream);
    hist_kernel<<<egrid, 256, 0, stream>>>(edges, cnt);
    scanA_kernel<<<sg, 256, 0, stream>>>(cnt, rowptr, bsum);
    scanB_kernel<<<1, 128, 0, stream>>>(bsum, boff);
    scanC_kernel<<<sg, 256, 0, stream>>>(cnt, rowptr, boff, cursor);
    scatter_kernel<<<egrid, 256, 0, stream>>>(edges, cursor, csr_s);

    // ---- layer 1 ----
    hipMemsetAsync(el, 0, NN*4*4, stream);
    hipMemsetAsync(er, 0, NN*4*4, stream);
    gemm_attn_kernel<4><<<dim3(313, 4), 256, 0, stream>>>(x, W1, al1, ar1, feat, el, er, NN);
    agg_kernel<4, true><<<dim3(NN, MM), 256, 0, stream>>>(feat, el, er, rowptr, csr_s, z);
    hipMemsetAsync(wsum, 0, 16, stream);
    semw_kernel<<<938, 256, 0, stream>>>(z, saW1, sab1, sav1, wsum);
    beta_kernel<<<1, 64, 0, stream>>>(wsum, beta, nullptr);
    combine_kernel<<<NN, 256, 0, stream>>>(z, beta, h);

    // ---- layer 2 ----
    hipMemsetAsync(el, 0, NN*4, stream);
    hipMemsetAsync(er, 0, NN*4, stream);
    gemm_attn_kernel<1><<<dim3(313, 4), 256, 0, stream>>>(h, W2, al2, ar2, feat, el, er, NN);
    agg_kernel<1, false><<<dim3(NN, MM), 256, 0, stream>>>(feat, el, er, rowptr, csr_s, z);
    hipMemsetAsync(wsum, 0, 16, stream);
    semw_kernel<<<938, 256, 0, stream>>>(z, saW2, sab2, sav2, wsum);
    beta_kernel<<<1, 64, 0, stream>>>(wsum, beta, out + (size_t)NN*256);
    combine_kernel<<<NN, 256, 0, stream>>>(z, beta, out);
}

// Round 4
// 530.020 us; speedup vs baseline: 2.7800x; 1.1454x over previous
//
#include <hip/hip_runtime.h>
#include <hip/hip_bf16.h>
#include <math.h>

#define NN 20000
#define EE 320000
#define MM 3
#define FW 256        // NH*HID = NHO*OUT = 256
#define SAH 128
#define NB 79         // ceil(NN/256)

static __device__ __forceinline__ float lrelu(float x){ return x > 0.f ? x : 0.2f*x; }

// fp32 -> bf16 round-to-nearest-even (values are finite/small; no NaN handling needed)
static __device__ __forceinline__ unsigned short f2bf(float f) {
    unsigned u = __float_as_uint(f);
    return (unsigned short)((u + 0x7FFFu + ((u >> 16) & 1u)) >> 16);
}
static __device__ __forceinline__ float bf2f(unsigned short b) {
    return __uint_as_float(((unsigned)b) << 16);
}

// ---------------- CSR build ----------------
__global__ __launch_bounds__(256) void hist_kernel(const int* __restrict__ edges, int* __restrict__ cnt) {
    int idx = blockIdx.x*256 + threadIdx.x;
    if (idx >= MM*EE) return;
    int m = idx / EE, e = idx - m*EE;
    int dst = edges[(m*2+1)*EE + e];
    atomicAdd(&cnt[m*NN + dst], 1);
}

__global__ __launch_bounds__(256) void scanA_kernel(const int* __restrict__ cnt, int* __restrict__ rowptr, int* __restrict__ bsum) {
    int m = blockIdx.y;
    int i = blockIdx.x*256 + threadIdx.x;
    int v = (i < NN) ? cnt[m*NN + i] : 0;
    int lane = threadIdx.x & 63;
    int val = v;
    #pragma unroll
    for (int o = 1; o < 64; o <<= 1) { int t = __shfl_up(val, o); if (lane >= o) val += t; }
    __shared__ int ws[4];
    int w = threadIdx.x >> 6;
    if (lane == 63) ws[w] = val;
    __syncthreads();
    #pragma unroll
    for (int j = 0; j < 3; ++j) if (j < w) val += ws[j];
    if (i < NN) rowptr[m*(NN+1) + 1 + i] = val;
    if (threadIdx.x == 255) bsum[m*NB + blockIdx.x] = val;
}

__global__ __launch_bounds__(128) void scanB_kernel(const int* __restrict__ bsum, int* __restrict__ boff) {
    __shared__ int s[128];
    int t = threadIdx.x;
    for (int m = 0; m < MM; ++m) {
        int v = (t < NB) ? bsum[m*NB + t] : 0;
        s[t] = v; __syncthreads();
        for (int o = 1; o < 128; o <<= 1) {
            int x = (t >= o) ? s[t - o] : 0;
            __syncthreads();
            s[t] += x;
            __syncthreads();
        }
        if (t < NB) boff[m*NB + t] = s[t] - v;   // exclusive
        __syncthreads();
    }
}

__global__ __launch_bounds__(256) void scanC_kernel(const int* __restrict__ cnt, int* __restrict__ rowptr,
                                                    const int* __restrict__ boff, int* __restrict__ cursor) {
    int m = blockIdx.y;
    int i = blockIdx.x*256 + threadIdx.x;
    if (i >= NN) return;
    int incl = rowptr[m*(NN+1) + 1 + i] + boff[m*NB + blockIdx.x];
    rowptr[m*(NN+1) + 1 + i] = incl;
    cursor[m*NN + i] = incl - cnt[m*NN + i];
    if (i == 0 && blockIdx.x == 0) rowptr[m*(NN+1)] = 0;
}

__global__ __launch_bounds__(256) void scatter_kernel(const int* __restrict__ edges, int* __restrict__ cursor,
                                                      int* __restrict__ csr_src, int* __restrict__ csr_dst) {
    int idx = blockIdx.x*256 + threadIdx.x;
    if (idx >= MM*EE) return;
    int m = idx / EE, e = idx - m*EE;
    int src = edges[m*2*EE + e];
    int dst = edges[(m*2+1)*EE + e];
    int pos = atomicAdd(&cursor[m*NN + dst], 1);
    csr_src[m*EE + pos] = src;
    csr_dst[m*EE + pos] = dst;
}

// ---------------- GEMM (C = A@B) + el/er epilogue; C written as bf16 ----------------
// A:[Mrows,256] B:[256,256] C:[Mrows,256] bf16; attl/attr flat [H*D]=[256]
template<int H>
__global__ __launch_bounds__(256) void gemm_attn_kernel(const float* __restrict__ A, const float* __restrict__ B,
                                                        const float* __restrict__ attl, const float* __restrict__ attr,
                                                        unsigned short* __restrict__ C, float* __restrict__ el,
                                                        float* __restrict__ er, int Mrows) {
    __shared__ float As[16][68];
    __shared__ float Bs[16][68];
    int tid = threadIdx.x;
    int tx = tid & 15, ty = tid >> 4;
    int row0 = blockIdx.x*64, col0 = blockIdx.y*64;
    float c[4][4] = {};
    int arow = row0 + (tid >> 2);
    int arl  = tid >> 2;
    int ak   = (tid & 3) * 4;
    int bkr  = tid >> 4, bcc = (tid & 15) * 4;

    for (int k0 = 0; k0 < 256; k0 += 16) {
        float4 av = make_float4(0.f,0.f,0.f,0.f);
        if (arow < Mrows) av = *(const float4*)&A[(size_t)arow*256 + k0 + ak];
        As[ak+0][arl] = av.x; As[ak+1][arl] = av.y; As[ak+2][arl] = av.z; As[ak+3][arl] = av.w;
        float4 bv = *(const float4*)&B[(size_t)(k0 + bkr)*256 + col0 + bcc];
        *(float4*)&Bs[bkr][bcc] = bv;
        __syncthreads();
        #pragma unroll
        for (int k = 0; k < 16; ++k) {
            float4 a = *(float4*)&As[k][ty*4];
            float4 b = *(float4*)&Bs[k][tx*4];
            c[0][0] += a.x*b.x; c[0][1] += a.x*b.y; c[0][2] += a.x*b.z; c[0][3] += a.x*b.w;
            c[1][0] += a.y*b.x; c[1][1] += a.y*b.y; c[1][2] += a.y*b.z; c[1][3] += a.y*b.w;
            c[2][0] += a.z*b.x; c[2][1] += a.z*b.y; c[2][2] += a.z*b.z; c[2][3] += a.z*b.w;
            c[3][0] += a.w*b.x; c[3][1] += a.w*b.y; c[3][2] += a.w*b.z; c[3][3] += a.w*b.w;
        }
        __syncthreads();
    }

    float alv[4], arv[4];
    #pragma unroll
    for (int j = 0; j < 4; ++j) { alv[j] = attl[col0 + tx*4 + j]; arv[j] = attr[col0 + tx*4 + j]; }
    int h = (H == 4) ? (int)blockIdx.y : 0;
    #pragma unroll
    for (int i = 0; i < 4; ++i) {
        int r = row0 + ty*4 + i;
        float pel = c[i][0]*alv[0] + c[i][1]*alv[1] + c[i][2]*alv[2] + c[i][3]*alv[3];
        float per = c[i][0]*arv[0] + c[i][1]*arv[1] + c[i][2]*arv[2] + c[i][3]*arv[3];
        #pragma unroll
        for (int o = 1; o < 16; o <<= 1) { pel += __shfl_xor(pel, o); per += __shfl_xor(per, o); }
        if (r < Mrows) {
            ushort4 cv;
            cv.x = f2bf(c[i][0]); cv.y = f2bf(c[i][1]); cv.z = f2bf(c[i][2]); cv.w = f2bf(c[i][3]);
            *(ushort4*)&C[(size_t)r*256 + col0 + tx*4] = cv;
            if (tx == 0) { atomicAdd(&el[r*H + h], pel); atomicAdd(&er[r*H + h], per); }
        }
    }
}

// ---------------- edge coefficients ee = exp(leakyrelu(el[src]+er[dst])) ----------------
template<int H>
__global__ __launch_bounds__(256) void edge_ee_kernel(const int* __restrict__ csr_src, const int* __restrict__ csr_dst,
                                                      const float* __restrict__ el, const float* __restrict__ er,
                                                      float* __restrict__ ee) {
    int idx = blockIdx.x*256 + threadIdx.x;
    if (idx >= MM*EE) return;
    int src = csr_src[idx], dst = csr_dst[idx];
    if (H == 4) {
        float4 l = *(const float4*)&el[src*4];
        float4 r = *(const float4*)&er[dst*4];
        float4 s;
        s.x = expf(lrelu(l.x + r.x));
        s.y = expf(lrelu(l.y + r.y));
        s.z = expf(lrelu(l.z + r.z));
        s.w = expf(lrelu(l.w + r.w));
        *(float4*)&ee[(size_t)idx*4] = s;
    } else {
        ee[idx] = expf(lrelu(el[src] + er[dst]));
    }
}

// ---------------- per-dst aggregation ----------------
// One wave per (node, metapath): block = 4 waves = 4 consecutive nodes.
// z[n,m,:] = (sum_e ee*feat[src_e]) / (sum_e ee); 2 feat gathers in flight,
// src/ee prefetched 4 ahead. Lane holds features [lane*4, lane*4+4).
template<int H, bool RELU>
__global__ __launch_bounds__(256) void agg_kernel(const unsigned short* __restrict__ feat,
                                                  const float* __restrict__ ee,
                                                  const int* __restrict__ rowptr,
                                                  const int* __restrict__ csr_src,
                                                  float* __restrict__ z) {
    int m = blockIdx.y;
    int tid = threadIdx.x;
    int lane = tid & 63, wv = tid >> 6;
    int n = blockIdx.x * 4 + wv;
    int h = (H == 4) ? (lane >> 4) : 0;
    int beg = rowptr[m*(NN+1) + n], end = rowptr[m*(NN+1) + n + 1];
    const int eb = m*EE;

    float a0=0.f, a1=0.f, a2=0.f, a3=0.f, den=0.f;
    int   sA=0, sB=0, sC=0, sD=0;
    float wA=0.f, wB=0.f, wC=0.f, wD=0.f;

    if (beg   < end) { sA = csr_src[eb+beg  ]; wA = (H==4)? ee[(size_t)(eb+beg  )*4+h] : ee[eb+beg  ]; }
    if (beg+1 < end) { sB = csr_src[eb+beg+1]; wB = (H==4)? ee[(size_t)(eb+beg+1)*4+h] : ee[eb+beg+1]; }
    if (beg+2 < end) { sC = csr_src[eb+beg+2]; wC = (H==4)? ee[(size_t)(eb+beg+2)*4+h] : ee[eb+beg+2]; }
    if (beg+3 < end) { sD = csr_src[eb+beg+3]; wD = (H==4)? ee[(size_t)(eb+beg+3)*4+h] : ee[eb+beg+3]; }

    for (int e = beg; e < end; e += 2) {
        // two gathers in flight
        ushort4 v0 = *(const ushort4*)(feat + (size_t)sA*256 + lane*4);
        bool has1 = (e + 1 < end);
        ushort4 v1 = make_ushort4(0,0,0,0);
        if (has1) v1 = *(const ushort4*)(feat + (size_t)sB*256 + lane*4);
        float w0 = wA, w1 = has1 ? wB : 0.f;
        sA = sC; wA = wC; sB = sD; wB = wD;
        if (e+4 < end) { sC = csr_src[eb+e+4]; wC = (H==4)? ee[(size_t)(eb+e+4)*4+h] : ee[eb+e+4]; }
        if (e+5 < end) { sD = csr_src[eb+e+5]; wD = (H==4)? ee[(size_t)(eb+e+5)*4+h] : ee[eb+e+5]; }
        den += w0 + w1;
        a0 += w0*bf2f(v0.x) + w1*bf2f(v1.x);
        a1 += w0*bf2f(v0.y) + w1*bf2f(v1.y);
        a2 += w0*bf2f(v0.z) + w1*bf2f(v1.z);
        a3 += w0*bf2f(v0.w) + w1*bf2f(v1.w);
    }

    float inv = 1.f / (den + 1e-9f);
    float4 o = make_float4(a0*inv, a1*inv, a2*inv, a3*inv);
    if (RELU) { o.x=fmaxf(o.x,0.f); o.y=fmaxf(o.y,0.f); o.z=fmaxf(o.z,0.f); o.w=fmaxf(o.w,0.f); }
    *(float4*)&z[((size_t)n*MM + m)*256 + lane*4] = o;
}

// ---------------- semantic attention: wsum[m] += sum_n tanh(z@W+b)·v ----------------
__global__ __launch_bounds__(256) void semw_kernel(const float* __restrict__ Z, const float* __restrict__ W,
                                                   const float* __restrict__ bias, const float* __restrict__ v,
                                                   float* __restrict__ wsum) {
    __shared__ float As[16][68];
    __shared__ float Bs[16][132];
    int tid = threadIdx.x;
    int tx = tid & 31, ty = tid >> 5;   // 32 x 8
    int row0 = blockIdx.x * 64;
    float c[8][4] = {};
    int arl = tid >> 2, arow = row0 + arl, ak = (tid & 3)*4;
    int bkr = tid >> 4, bcc = (tid & 15) * 8;

    for (int k0 = 0; k0 < 256; k0 += 16) {
        float4 av = make_float4(0.f,0.f,0.f,0.f);
        if (arow < NN*MM) av = *(const float4*)&Z[(size_t)arow*256 + k0 + ak];
        As[ak+0][arl] = av.x; As[ak+1][arl] = av.y; As[ak+2][arl] = av.z; As[ak+3][arl] = av.w;
        float4 b0 = *(const float4*)&W[(size_t)(k0 + bkr)*SAH + bcc];
        float4 b1 = *(const float4*)&W[(size_t)(k0 + bkr)*SAH + bcc + 4];
        *(float4*)&Bs[bkr][bcc]     = b0;
        *(float4*)&Bs[bkr][bcc + 4] = b1;
        __syncthreads();
        #pragma unroll
        for (int k = 0; k < 16; ++k) {
            float4 a0 = *(float4*)&As[k][ty*8];
            float4 a1 = *(float4*)&As[k][ty*8 + 4];
            float4 b  = *(float4*)&Bs[k][tx*4];
            float aa[8] = {a0.x,a0.y,a0.z,a0.w,a1.x,a1.y,a1.z,a1.w};
            #pragma unroll
            for (int i = 0; i < 8; ++i) {
                c[i][0] += aa[i]*b.x; c[i][1] += aa[i]*b.y; c[i][2] += aa[i]*b.z; c[i][3] += aa[i]*b.w;
            }
        }
        __syncthreads();
    }

    float bb[4], vv[4];
    #pragma unroll
    for (int j = 0; j < 4; ++j) { bb[j] = bias[tx*4 + j]; vv[j] = v[tx*4 + j]; }

    float loc[3] = {0.f, 0.f, 0.f};
    #pragma unroll
    for (int i = 0; i < 8; ++i) {
        int row = row0 + ty*8 + i;
        float p = tanhf(c[i][0] + bb[0]) * vv[0] + tanhf(c[i][1] + bb[1]) * vv[1]
                + tanhf(c[i][2] + bb[2]) * vv[2] + tanhf(c[i][3] + bb[3]) * vv[3];
        #pragma unroll
        for (int o = 1; o < 32; o <<= 1) p += __shfl_xor(p, o);
        if (tx == 0 && row < NN*MM) loc[row % MM] += p;
    }
    __shared__ float red[8][3];
    if (tx == 0) { red[ty][0] = loc[0]; red[ty][1] = loc[1]; red[ty][2] = loc[2]; }
    __syncthreads();
    if (tid < MM) {
        float s = 0.f;
        #pragma unroll
        for (int j = 0; j < 8; ++j) s += red[j][tid];
        atomicAdd(&wsum[tid], s);
    }
}

__global__ void beta_kernel(const float* __restrict__ wsum, float* __restrict__ beta, float* att_out) {
    if (threadIdx.x == 0 && blockIdx.x == 0) {
        float w0 = wsum[0] / (float)NN, w1 = wsum[1] / (float)NN, w2 = wsum[2] / (float)NN;
        float mx = fmaxf(w0, fmaxf(w1, w2));
        float e0 = expf(w0 - mx), e1 = expf(w1 - mx), e2 = expf(w2 - mx);
        float s = e0 + e1 + e2;
        beta[0] = e0 / s; beta[1] = e1 / s; beta[2] = e2 / s;
        if (att_out) { att_out[0] = e0/s; att_out[1] = e1/s; att_out[2] = e2/s; }
    }
}

__global__ __launch_bounds__(256) void combine_kernel(const float* __restrict__ z, const float* __restrict__ beta,
                                                      float* __restrict__ out) {
    int n = blockIdx.x, d = threadIdx.x;
    float b0 = beta[0], b1 = beta[1], b2 = beta[2];
    size_t base = (size_t)n*MM*256 + d;
    out[(size_t)n*256 + d] = b0*z[base] + b1*z[base + 256] + b2*z[base + 512];
}

extern "C" void kernel_launch(void* const* d_in, const int* in_sizes, int n_in,
                              void* d_out, int out_size, void* d_ws, size_t ws_size,
                              hipStream_t stream) {
    const float* x    = (const float*)d_in[0];
    const int*   edges= (const int*)  d_in[1];
    const float* W1   = (const float*)d_in[2];
    const float* al1  = (const float*)d_in[3];
    const float* ar1  = (const float*)d_in[4];
    const float* saW1 = (const float*)d_in[5];
    const float* sab1 = (const float*)d_in[6];
    const float* sav1 = (const float*)d_in[7];
    const float* W2   = (const float*)d_in[8];
    const float* al2  = (const float*)d_in[9];
    const float* ar2  = (const float*)d_in[10];
    const float* saW2 = (const float*)d_in[11];
    const float* sab2 = (const float*)d_in[12];
    const float* sav2 = (const float*)d_in[13];
    float* out = (float*)d_out;

    char* ws = (char*)d_ws;
    size_t off = 0;
    auto alloc = [&](size_t bytes) { void* p = ws + off; off += (bytes + 255) & ~(size_t)255; return p; };
    unsigned short* feat = (unsigned short*)alloc((size_t)NN*256*2);   // bf16
    float* z      = (float*)alloc((size_t)NN*MM*256*4);
    float* ee     = (float*)alloc((size_t)MM*EE*4*4);
    float* el     = (float*)alloc(NN*4*4);
    float* er     = (float*)alloc(NN*4*4);
    float* wsum   = (float*)alloc(256);
    float* beta   = (float*)alloc(256);
    int*   cnt    = (int*)alloc(MM*NN*4);
    int*   cursor = (int*)alloc(MM*NN*4);
    int*   rowptr = (int*)alloc(MM*(NN+1)*4);
    int*   csr_s  = (int*)alloc((size_t)MM*EE*4);
    int*   csr_d  = (int*)alloc((size_t)MM*EE*4);
    int*   bsum   = (int*)alloc(MM*NB*4);
    int*   boff   = (int*)alloc(MM*NB*4);
    float* h = out;  // reuse d_out as layer-1 output buffer (fully overwritten at the end)

    int egrid = (MM*EE + 255)/256;
    dim3 sg(NB, MM);

    // CSR build (shared by both layers)
    hipMemsetAsync(cnt, 0, MM*NN*4, stream);
    hist_kernel<<<egrid, 256, 0, stream>>>(edges, cnt);
    scanA_kernel<<<sg, 256, 0, stream>>>(cnt, rowptr, bsum);
    scanB_kernel<<<1, 128, 0, stream>>>(bsum, boff);
    scanC_kernel<<<sg, 256, 0, stream>>>(cnt, rowptr, boff, cursor);
    scatter_kernel<<<egrid, 256, 0, stream>>>(edges, cursor, csr_s, csr_d);

    // ---- layer 1 ----
    hipMemsetAsync(el, 0, NN*4*4, stream);
    hipMemsetAsync(er, 0, NN*4*4, stream);
    gemm_attn_kernel<4><<<dim3(313, 4), 256, 0, stream>>>(x, W1, al1, ar1, feat, el, er, NN);
    edge_ee_kernel<4><<<egrid, 256, 0, stream>>>(csr_s, csr_d, el, er, ee);
    agg_kernel<4, true><<<dim3(NN/4, MM), 256, 0, stream>>>(feat, ee, rowptr, csr_s, z);
    hipMemsetAsync(wsum, 0, 16, stream);
    semw_kernel<<<938, 256, 0, stream>>>(z, saW1, sab1, sav1, wsum);
    beta_kernel<<<1, 64, 0, stream>>>(wsum, beta, nullptr);
    combine_kernel<<<NN, 256, 0, stream>>>(z, beta, h);

    // ---- layer 2 ----
    hipMemsetAsync(el, 0, NN*4, stream);
    hipMemsetAsync(er, 0, NN*4, stream);
    gemm_attn_kernel<1><<<dim3(313, 4), 256, 0, stream>>>(h, W2, al2, ar2, feat, el, er, NN);
    edge_ee_kernel<1><<<egrid, 256, 0, stream>>>(csr_s, csr_d, el, er, ee);
    agg_kernel<1, false><<<dim3(NN/4, MM), 256, 0, stream>>>(feat, ee, rowptr, csr_s, z);
    hipMemsetAsync(wsum, 0, 16, stream);
    semw_kernel<<<938, 256, 0, stream>>>(z, saW2, sab2, sav2, wsum);
    beta_kernel<<<1, 64, 0, stream>>>(wsum, beta, out + (size_t)NN*256);
    combine_kernel<<<NN, 256, 0, stream>>>(z, beta, out);
}

// Round 5
// 482.466 us; speedup vs baseline: 3.0540x; 1.0986x over previous
//
#include <hip/hip_runtime.h>
#include <hip/hip_bf16.h>
#include <math.h>

#define NN 20000
#define EE 320000
#define MM 3
#define FW 256        // NH*HID = NHO*OUT = 256
#define SAH 128
#define NB 79         // ceil(NN/256)

static __device__ __forceinline__ float lrelu(float x){ return x > 0.f ? x : 0.2f*x; }

// fp32 -> bf16 round-to-nearest-even (values are finite/small; no NaN handling needed)
static __device__ __forceinline__ unsigned short f2bf(float f) {
    unsigned u = __float_as_uint(f);
    return (unsigned short)((u + 0x7FFFu + ((u >> 16) & 1u)) >> 16);
}
static __device__ __forceinline__ float bf2f(unsigned short b) {
    return __uint_as_float(((unsigned)b) << 16);
}
static __device__ __forceinline__ float bflo(unsigned u){ return __uint_as_float(u << 16); }
static __device__ __forceinline__ float bfhi(unsigned u){ return __uint_as_float(u & 0xffff0000u); }
static __device__ __forceinline__ unsigned pk2bf(float lo, float hi) {
    return ((unsigned)f2bf(lo)) | (((unsigned)f2bf(hi)) << 16);
}

// ---------------- CSR build ----------------
__global__ __launch_bounds__(256) void hist_kernel(const int* __restrict__ edges, int* __restrict__ cnt) {
    int idx = blockIdx.x*256 + threadIdx.x;
    if (idx >= MM*EE) return;
    int m = idx / EE, e = idx - m*EE;
    int dst = edges[(m*2+1)*EE + e];
    atomicAdd(&cnt[m*NN + dst], 1);
}

__global__ __launch_bounds__(256) void scanA_kernel(const int* __restrict__ cnt, int* __restrict__ rowptr, int* __restrict__ bsum) {
    int m = blockIdx.y;
    int i = blockIdx.x*256 + threadIdx.x;
    int v = (i < NN) ? cnt[m*NN + i] : 0;
    int lane = threadIdx.x & 63;
    int val = v;
    #pragma unroll
    for (int o = 1; o < 64; o <<= 1) { int t = __shfl_up(val, o); if (lane >= o) val += t; }
    __shared__ int ws[4];
    int w = threadIdx.x >> 6;
    if (lane == 63) ws[w] = val;
    __syncthreads();
    #pragma unroll
    for (int j = 0; j < 3; ++j) if (j < w) val += ws[j];
    if (i < NN) rowptr[m*(NN+1) + 1 + i] = val;
    if (threadIdx.x == 255) bsum[m*NB + blockIdx.x] = val;
}

__global__ __launch_bounds__(128) void scanB_kernel(const int* __restrict__ bsum, int* __restrict__ boff) {
    __shared__ int s[128];
    int t = threadIdx.x;
    for (int m = 0; m < MM; ++m) {
        int v = (t < NB) ? bsum[m*NB + t] : 0;
        s[t] = v; __syncthreads();
        for (int o = 1; o < 128; o <<= 1) {
            int x = (t >= o) ? s[t - o] : 0;
            __syncthreads();
            s[t] += x;
            __syncthreads();
        }
        if (t < NB) boff[m*NB + t] = s[t] - v;   // exclusive
        __syncthreads();
    }
}

__global__ __launch_bounds__(256) void scanC_kernel(const int* __restrict__ cnt, int* __restrict__ rowptr,
                                                    const int* __restrict__ boff, int* __restrict__ cursor) {
    int m = blockIdx.y;
    int i = blockIdx.x*256 + threadIdx.x;
    if (i >= NN) return;
    int incl = rowptr[m*(NN+1) + 1 + i] + boff[m*NB + blockIdx.x];
    rowptr[m*(NN+1) + 1 + i] = incl;
    cursor[m*NN + i] = incl - cnt[m*NN + i];
    if (i == 0 && blockIdx.x == 0) rowptr[m*(NN+1)] = 0;
}

__global__ __launch_bounds__(256) void scatter_kernel(const int* __restrict__ edges, int* __restrict__ cursor,
                                                      int* __restrict__ csr_src, int* __restrict__ csr_dst) {
    int idx = blockIdx.x*256 + threadIdx.x;
    if (idx >= MM*EE) return;
    int m = idx / EE, e = idx - m*EE;
    int src = edges[m*2*EE + e];
    int dst = edges[(m*2+1)*EE + e];
    int pos = atomicAdd(&cursor[m*NN + dst], 1);
    csr_src[m*EE + pos] = src;
    csr_dst[m*EE + pos] = dst;
}

// ---------------- GEMM (C = A@B) + el/er epilogue; C written as bf16 ----------------
// A:[Mrows,256] B:[256,256] C:[Mrows,256] bf16; attl/attr flat [H*D]=[256]
template<int H>
__global__ __launch_bounds__(256) void gemm_attn_kernel(const float* __restrict__ A, const float* __restrict__ B,
                                                        const float* __restrict__ attl, const float* __restrict__ attr,
                                                        unsigned short* __restrict__ C, float* __restrict__ el,
                                                        float* __restrict__ er, int Mrows) {
    __shared__ float As[16][68];
    __shared__ float Bs[16][68];
    int tid = threadIdx.x;
    int tx = tid & 15, ty = tid >> 4;
    int row0 = blockIdx.x*64, col0 = blockIdx.y*64;
    float c[4][4] = {};
    int arow = row0 + (tid >> 2);
    int arl  = tid >> 2;
    int ak   = (tid & 3) * 4;
    int bkr  = tid >> 4, bcc = (tid & 15) * 4;

    for (int k0 = 0; k0 < 256; k0 += 16) {
        float4 av = make_float4(0.f,0.f,0.f,0.f);
        if (arow < Mrows) av = *(const float4*)&A[(size_t)arow*256 + k0 + ak];
        As[ak+0][arl] = av.x; As[ak+1][arl] = av.y; As[ak+2][arl] = av.z; As[ak+3][arl] = av.w;
        float4 bv = *(const float4*)&B[(size_t)(k0 + bkr)*256 + col0 + bcc];
        *(float4*)&Bs[bkr][bcc] = bv;
        __syncthreads();
        #pragma unroll
        for (int k = 0; k < 16; ++k) {
            float4 a = *(float4*)&As[k][ty*4];
            float4 b = *(float4*)&Bs[k][tx*4];
            c[0][0] += a.x*b.x; c[0][1] += a.x*b.y; c[0][2] += a.x*b.z; c[0][3] += a.x*b.w;
            c[1][0] += a.y*b.x; c[1][1] += a.y*b.y; c[1][2] += a.y*b.z; c[1][3] += a.y*b.w;
            c[2][0] += a.z*b.x; c[2][1] += a.z*b.y; c[2][2] += a.z*b.z; c[2][3] += a.z*b.w;
            c[3][0] += a.w*b.x; c[3][1] += a.w*b.y; c[3][2] += a.w*b.z; c[3][3] += a.w*b.w;
        }
        __syncthreads();
    }

    float alv[4], arv[4];
    #pragma unroll
    for (int j = 0; j < 4; ++j) { alv[j] = attl[col0 + tx*4 + j]; arv[j] = attr[col0 + tx*4 + j]; }
    int h = (H == 4) ? (int)blockIdx.y : 0;
    #pragma unroll
    for (int i = 0; i < 4; ++i) {
        int r = row0 + ty*4 + i;
        float pel = c[i][0]*alv[0] + c[i][1]*alv[1] + c[i][2]*alv[2] + c[i][3]*alv[3];
        float per = c[i][0]*arv[0] + c[i][1]*arv[1] + c[i][2]*arv[2] + c[i][3]*arv[3];
        #pragma unroll
        for (int o = 1; o < 16; o <<= 1) { pel += __shfl_xor(pel, o); per += __shfl_xor(per, o); }
        if (r < Mrows) {
            ushort4 cv;
            cv.x = f2bf(c[i][0]); cv.y = f2bf(c[i][1]); cv.z = f2bf(c[i][2]); cv.w = f2bf(c[i][3]);
            *(ushort4*)&C[(size_t)r*256 + col0 + tx*4] = cv;
            if (tx == 0) { atomicAdd(&el[r*H + h], pel); atomicAdd(&er[r*H + h], per); }
        }
    }
}

// ---------------- edge coefficients ee = exp(leakyrelu(el[src]+er[dst])) ----------------
template<int H>
__global__ __launch_bounds__(256) void edge_ee_kernel(const int* __restrict__ csr_src, const int* __restrict__ csr_dst,
                                                      const float* __restrict__ el, const float* __restrict__ er,
                                                      float* __restrict__ ee) {
    int idx = blockIdx.x*256 + threadIdx.x;
    if (idx >= MM*EE) return;
    int src = csr_src[idx], dst = csr_dst[idx];
    if (H == 4) {
        float4 l = *(const float4*)&el[src*4];
        float4 r = *(const float4*)&er[dst*4];
        float4 s;
        s.x = expf(lrelu(l.x + r.x));
        s.y = expf(lrelu(l.y + r.y));
        s.z = expf(lrelu(l.z + r.z));
        s.w = expf(lrelu(l.w + r.w));
        *(float4*)&ee[(size_t)idx*4] = s;
    } else {
        ee[idx] = expf(lrelu(el[src] + er[dst]));
    }
}

// ---------------- per-dst aggregation ----------------
// One wave per (node, metapath); block = 4 waves = 4 consecutive nodes.
// Wave split into 2 edge-slots of 32 lanes; each lane covers 8 features
// (16B uint4 load), so one wave processes 2 edges per iteration with
// 2-deep scalar prefetch. Output z written as packed bf16.
template<int H, bool RELU>
__global__ __launch_bounds__(256) void agg_kernel(const unsigned short* __restrict__ feat,
                                                  const float* __restrict__ ee,
                                                  const int* __restrict__ rowptr,
                                                  const int* __restrict__ csr_src,
                                                  unsigned short* __restrict__ z) {
    int m = blockIdx.y;
    int tid = threadIdx.x;
    int lane = tid & 63, wv = tid >> 6;
    int n = blockIdx.x * 4 + wv;
    int eslot = lane >> 5, flane = lane & 31;
    int h = (H == 4) ? (flane >> 3) : 0;   // feature block flane*8 -> head (flane*8)/64
    int beg = rowptr[m*(NN+1) + n], end = rowptr[m*(NN+1) + n + 1];
    const int eb = m*EE;

    float a[8] = {};
    float den = 0.f;
    int e0 = beg + eslot;

    int   sA = 0, sB = 0;
    float wA = 0.f, wB = 0.f;
    if (e0 < end)     { sA = csr_src[eb+e0];   wA = (H==4)? ee[(size_t)(eb+e0  )*4+h] : ee[eb+e0  ]; }
    if (e0 + 2 < end) { sB = csr_src[eb+e0+2]; wB = (H==4)? ee[(size_t)(eb+e0+2)*4+h] : ee[eb+e0+2]; }

    for (int e = e0; e < end; e += 2) {
        uint4 v = *(const uint4*)(feat + (size_t)sA*256 + flane*8);
        float w = wA;
        sA = sB; wA = wB;
        if (e + 4 < end) {
            sB = csr_src[eb+e+4];
            wB = (H==4)? ee[(size_t)(eb+e+4)*4+h] : ee[eb+e+4];
        }
        den += w;
        a[0] += w * bflo(v.x); a[1] += w * bfhi(v.x);
        a[2] += w * bflo(v.y); a[3] += w * bfhi(v.y);
        a[4] += w * bflo(v.z); a[5] += w * bfhi(v.z);
        a[6] += w * bflo(v.w); a[7] += w * bfhi(v.w);
    }

    // combine the two edge-slots (lane ^ 32 holds the other slot's partial)
    #pragma unroll
    for (int j = 0; j < 8; ++j) a[j] += __shfl_xor(a[j], 32);
    den += __shfl_xor(den, 32);

    if (eslot == 0) {
        float inv = 1.f / (den + 1e-9f);
        #pragma unroll
        for (int j = 0; j < 8; ++j) {
            a[j] *= inv;
            if (RELU) a[j] = fmaxf(a[j], 0.f);
        }
        uint4 pk;
        pk.x = pk2bf(a[0], a[1]);
        pk.y = pk2bf(a[2], a[3]);
        pk.z = pk2bf(a[4], a[5]);
        pk.w = pk2bf(a[6], a[7]);
        *(uint4*)&z[((size_t)n*MM + m)*256 + flane*8] = pk;
    }
}

// ---------------- semantic attention: wsum[m] += sum_n tanh(z@W+b)·v ----------------
// Z is packed bf16 [N*M, 256]
__global__ __launch_bounds__(256) void semw_kernel(const unsigned short* __restrict__ Z, const float* __restrict__ W,
                                                   const float* __restrict__ bias, const float* __restrict__ v,
                                                   float* __restrict__ wsum) {
    __shared__ float As[16][68];
    __shared__ float Bs[16][132];
    int tid = threadIdx.x;
    int tx = tid & 31, ty = tid >> 5;   // 32 x 8
    int row0 = blockIdx.x * 64;
    float c[8][4] = {};
    int arl = tid >> 2, arow = row0 + arl, ak = (tid & 3)*4;
    int bkr = tid >> 4, bcc = (tid & 15) * 8;

    for (int k0 = 0; k0 < 256; k0 += 16) {
        float4 av = make_float4(0.f,0.f,0.f,0.f);
        if (arow < NN*MM) {
            uint2 zv = *(const uint2*)&Z[(size_t)arow*256 + k0 + ak];
            av.x = bflo(zv.x); av.y = bfhi(zv.x); av.z = bflo(zv.y); av.w = bfhi(zv.y);
        }
        As[ak+0][arl] = av.x; As[ak+1][arl] = av.y; As[ak+2][arl] = av.z; As[ak+3][arl] = av.w;
        float4 b0 = *(const float4*)&W[(size_t)(k0 + bkr)*SAH + bcc];
        float4 b1 = *(const float4*)&W[(size_t)(k0 + bkr)*SAH + bcc + 4];
        *(float4*)&Bs[bkr][bcc]     = b0;
        *(float4*)&Bs[bkr][bcc + 4] = b1;
        __syncthreads();
        #pragma unroll
        for (int k = 0; k < 16; ++k) {
            float4 a0 = *(float4*)&As[k][ty*8];
            float4 a1 = *(float4*)&As[k][ty*8 + 4];
            float4 b  = *(float4*)&Bs[k][tx*4];
            float aa[8] = {a0.x,a0.y,a0.z,a0.w,a1.x,a1.y,a1.z,a1.w};
            #pragma unroll
            for (int i = 0; i < 8; ++i) {
                c[i][0] += aa[i]*b.x; c[i][1] += aa[i]*b.y; c[i][2] += aa[i]*b.z; c[i][3] += aa[i]*b.w;
            }
        }
        __syncthreads();
    }

    float bb[4], vv[4];
    #pragma unroll
    for (int j = 0; j < 4; ++j) { bb[j] = bias[tx*4 + j]; vv[j] = v[tx*4 + j]; }

    float loc[3] = {0.f, 0.f, 0.f};
    #pragma unroll
    for (int i = 0; i < 8; ++i) {
        int row = row0 + ty*8 + i;
        float p = tanhf(c[i][0] + bb[0]) * vv[0] + tanhf(c[i][1] + bb[1]) * vv[1]
                + tanhf(c[i][2] + bb[2]) * vv[2] + tanhf(c[i][3] + bb[3]) * vv[3];
        #pragma unroll
        for (int o = 1; o < 32; o <<= 1) p += __shfl_xor(p, o);
        if (tx == 0 && row < NN*MM) loc[row % MM] += p;
    }
    __shared__ float red[8][3];
    if (tx == 0) { red[ty][0] = loc[0]; red[ty][1] = loc[1]; red[ty][2] = loc[2]; }
    __syncthreads();
    if (tid < MM) {
        float s = 0.f;
        #pragma unroll
        for (int j = 0; j < 8; ++j) s += red[j][tid];
        atomicAdd(&wsum[tid], s);
    }
}

__global__ void beta_kernel(const float* __restrict__ wsum, float* __restrict__ beta, float* att_out) {
    if (threadIdx.x == 0 && blockIdx.x == 0) {
        float w0 = wsum[0] / (float)NN, w1 = wsum[1] / (float)NN, w2 = wsum[2] / (float)NN;
        float mx = fmaxf(w0, fmaxf(w1, w2));
        float e0 = expf(w0 - mx), e1 = expf(w1 - mx), e2 = expf(w2 - mx);
        float s = e0 + e1 + e2;
        beta[0] = e0 / s; beta[1] = e1 / s; beta[2] = e2 / s;
        if (att_out) { att_out[0] = e0/s; att_out[1] = e1/s; att_out[2] = e2/s; }
    }
}

// z packed bf16; each thread handles 2 features (one dword per metapath)
__global__ __launch_bounds__(128) void combine_kernel(const unsigned short* __restrict__ z, const float* __restrict__ beta,
                                                      float* __restrict__ out) {
    int n = blockIdx.x, t = threadIdx.x;
    float b0 = beta[0], b1 = beta[1], b2 = beta[2];
    size_t base = (size_t)n*MM*256 + t*2;
    unsigned z0 = *(const unsigned*)&z[base];
    unsigned z1 = *(const unsigned*)&z[base + 256];
    unsigned z2 = *(const unsigned*)&z[base + 512];
    float2 o;
    o.x = b0*bflo(z0) + b1*bflo(z1) + b2*bflo(z2);
    o.y = b0*bfhi(z0) + b1*bfhi(z1) + b2*bfhi(z2);
    *(float2*)&out[(size_t)n*256 + t*2] = o;
}

extern "C" void kernel_launch(void* const* d_in, const int* in_sizes, int n_in,
                              void* d_out, int out_size, void* d_ws, size_t ws_size,
                              hipStream_t stream) {
    const float* x    = (const float*)d_in[0];
    const int*   edges= (const int*)  d_in[1];
    const float* W1   = (const float*)d_in[2];
    const float* al1  = (const float*)d_in[3];
    const float* ar1  = (const float*)d_in[4];
    const float* saW1 = (const float*)d_in[5];
    const float* sab1 = (const float*)d_in[6];
    const float* sav1 = (const float*)d_in[7];
    const float* W2   = (const float*)d_in[8];
    const float* al2  = (const float*)d_in[9];
    const float* ar2  = (const float*)d_in[10];
    const float* saW2 = (const float*)d_in[11];
    const float* sab2 = (const float*)d_in[12];
    const float* sav2 = (const float*)d_in[13];
    float* out = (float*)d_out;

    char* ws = (char*)d_ws;
    size_t off = 0;
    auto alloc = [&](size_t bytes) { void* p = ws + off; off += (bytes + 255) & ~(size_t)255; return p; };
    unsigned short* feat = (unsigned short*)alloc((size_t)NN*256*2);      // bf16
    unsigned short* z    = (unsigned short*)alloc((size_t)NN*MM*256*2);   // bf16
    float* ee     = (float*)alloc((size_t)MM*EE*4*4);
    float* el     = (float*)alloc(NN*4*4);
    float* er     = (float*)alloc(NN*4*4);
    float* wsum   = (float*)alloc(256);
    float* beta   = (float*)alloc(256);
    int*   cnt    = (int*)alloc(MM*NN*4);
    int*   cursor = (int*)alloc(MM*NN*4);
    int*   rowptr = (int*)alloc(MM*(NN+1)*4);
    int*   csr_s  = (int*)alloc((size_t)MM*EE*4);
    int*   csr_d  = (int*)alloc((size_t)MM*EE*4);
    int*   bsum   = (int*)alloc(MM*NB*4);
    int*   boff   = (int*)alloc(MM*NB*4);
    float* h = out;  // reuse d_out as layer-1 output buffer (fully overwritten at the end)

    int egrid = (MM*EE + 255)/256;
    dim3 sg(NB, MM);

    // CSR build (shared by both layers)
    hipMemsetAsync(cnt, 0, MM*NN*4, stream);
    hist_kernel<<<egrid, 256, 0, stream>>>(edges, cnt);
    scanA_kernel<<<sg, 256, 0, stream>>>(cnt, rowptr, bsum);
    scanB_kernel<<<1, 128, 0, stream>>>(bsum, boff);
    scanC_kernel<<<sg, 256, 0, stream>>>(cnt, rowptr, boff, cursor);
    scatter_kernel<<<egrid, 256, 0, stream>>>(edges, cursor, csr_s, csr_d);

    // ---- layer 1 ----
    hipMemsetAsync(el, 0, NN*4*4, stream);
    hipMemsetAsync(er, 0, NN*4*4, stream);
    gemm_attn_kernel<4><<<dim3(313, 4), 256, 0, stream>>>(x, W1, al1, ar1, feat, el, er, NN);
    edge_ee_kernel<4><<<egrid, 256, 0, stream>>>(csr_s, csr_d, el, er, ee);
    agg_kernel<4, true><<<dim3(NN/4, MM), 256, 0, stream>>>(feat, ee, rowptr, csr_s, z);
    hipMemsetAsync(wsum, 0, 16, stream);
    semw_kernel<<<938, 256, 0, stream>>>(z, saW1, sab1, sav1, wsum);
    beta_kernel<<<1, 64, 0, stream>>>(wsum, beta, nullptr);
    combine_kernel<<<NN, 128, 0, stream>>>(z, beta, h);

    // ---- layer 2 ----
    hipMemsetAsync(el, 0, NN*4, stream);
    hipMemsetAsync(er, 0, NN*4, stream);
    gemm_attn_kernel<1><<<dim3(313, 4), 256, 0, stream>>>(h, W2, al2, ar2, feat, el, er, NN);
    edge_ee_kernel<1><<<egrid, 256, 0, stream>>>(csr_s, csr_d, el, er, ee);
    agg_kernel<1, false><<<dim3(NN/4, MM), 256, 0, stream>>>(feat, ee, rowptr, csr_s, z);
    hipMemsetAsync(wsum, 0, 16, stream);
    semw_kernel<<<938, 256, 0, stream>>>(z, saW2, sab2, sav2, wsum);
    beta_kernel<<<1, 64, 0, stream>>>(wsum, beta, out + (size_t)NN*256);
    combine_kernel<<<NN, 128, 0, stream>>>(z, beta, out);
}

// Round 6
// 416.601 us; speedup vs baseline: 3.5368x; 1.1581x over previous
//
#include <hip/hip_runtime.h>
#include <hip/hip_bf16.h>
#include <math.h>

#define NN 20000
#define EE 320000
#define MM 3
#define FW 256        // NH*HID = NHO*OUT = 256
#define SAH 128
#define NB 79         // ceil(NN/256)

typedef __attribute__((ext_vector_type(8))) short bf16x8;
typedef __attribute__((ext_vector_type(4))) float f32x4;

static __device__ __forceinline__ float lrelu(float x){ return x > 0.f ? x : 0.2f*x; }

// fp32 -> bf16 round-to-nearest-even
static __device__ __forceinline__ unsigned short f2bf(float f) {
    unsigned u = __float_as_uint(f);
    return (unsigned short)((u + 0x7FFFu + ((u >> 16) & 1u)) >> 16);
}
static __device__ __forceinline__ float bflo(unsigned u){ return __uint_as_float(u << 16); }
static __device__ __forceinline__ float bfhi(unsigned u){ return __uint_as_float(u & 0xffff0000u); }
static __device__ __forceinline__ unsigned pk2bf(float lo, float hi) {
    return ((unsigned)f2bf(lo)) | (((unsigned)f2bf(hi)) << 16);
}

// ---------------- prep: x -> bf16; W1/saW1/W2/saW2 -> transposed bf16 [out][k] ----------------
#define XBLK 2500   // 2500*256 threads * 8 elems = 5.12M = NN*256
__global__ __launch_bounds__(256) void prep_kernel(const float* __restrict__ x, unsigned short* __restrict__ xb,
                                                   const float* __restrict__ W1, unsigned short* __restrict__ W1t,
                                                   const float* __restrict__ saW1, unsigned short* __restrict__ saW1t,
                                                   const float* __restrict__ W2, unsigned short* __restrict__ W2t,
                                                   const float* __restrict__ saW2, unsigned short* __restrict__ saW2t) {
    int b = blockIdx.x, tid = threadIdx.x;
    if (b < XBLK) {
        int i = b*256 + tid;           // uint4 index, 8 elems each
        const float4* p = (const float4*)x + (size_t)i*2;
        float4 v0 = p[0], v1 = p[1];
        uint4 o;
        o.x = pk2bf(v0.x, v0.y); o.y = pk2bf(v0.z, v0.w);
        o.z = pk2bf(v1.x, v1.y); o.w = pk2bf(v1.z, v1.w);
        ((uint4*)xb)[i] = o;
        return;
    }
    int b2 = b - XBLK;
    if (b2 < 256)      { int n = b2;       W1t  [(size_t)n*256 + tid] = f2bf(W1  [(size_t)tid*256 + n]); }
    else if (b2 < 384) { int n = b2 - 256; saW1t[(size_t)n*256 + tid] = f2bf(saW1[(size_t)tid*SAH + n]); }
    else if (b2 < 640) { int n = b2 - 384; W2t  [(size_t)n*256 + tid] = f2bf(W2  [(size_t)tid*256 + n]); }
    else               { int n = b2 - 640; saW2t[(size_t)n*256 + tid] = f2bf(saW2[(size_t)tid*SAH + n]); }
}

// ---------------- CSR build ----------------
__global__ __launch_bounds__(256) void hist_kernel(const int* __restrict__ edges, int* __restrict__ cnt) {
    int idx = blockIdx.x*256 + threadIdx.x;
    if (idx >= MM*EE) return;
    int m = idx / EE, e = idx - m*EE;
    int dst = edges[(m*2+1)*EE + e];
    atomicAdd(&cnt[m*NN + dst], 1);
}

__global__ __launch_bounds__(256) void scanA_kernel(const int* __restrict__ cnt, int* __restrict__ rowptr, int* __restrict__ bsum) {
    int m = blockIdx.y;
    int i = blockIdx.x*256 + threadIdx.x;
    int v = (i < NN) ? cnt[m*NN + i] : 0;
    int lane = threadIdx.x & 63;
    int val = v;
    #pragma unroll
    for (int o = 1; o < 64; o <<= 1) { int t = __shfl_up(val, o); if (lane >= o) val += t; }
    __shared__ int ws[4];
    int w = threadIdx.x >> 6;
    if (lane == 63) ws[w] = val;
    __syncthreads();
    #pragma unroll
    for (int j = 0; j < 3; ++j) if (j < w) val += ws[j];
    if (i < NN) rowptr[m*(NN+1) + 1 + i] = val;
    if (threadIdx.x == 255) bsum[m*NB + blockIdx.x] = val;
}

__global__ __launch_bounds__(128) void scanB_kernel(const int* __restrict__ bsum, int* __restrict__ boff) {
    __shared__ int s[128];
    int t = threadIdx.x;
    for (int m = 0; m < MM; ++m) {
        int v = (t < NB) ? bsum[m*NB + t] : 0;
        s[t] = v; __syncthreads();
        for (int o = 1; o < 128; o <<= 1) {
            int x = (t >= o) ? s[t - o] : 0;
            __syncthreads();
            s[t] += x;
            __syncthreads();
        }
        if (t < NB) boff[m*NB + t] = s[t] - v;   // exclusive
        __syncthreads();
    }
}

__global__ __launch_bounds__(256) void scanC_kernel(const int* __restrict__ cnt, int* __restrict__ rowptr,
                                                    const int* __restrict__ boff, int* __restrict__ cursor) {
    int m = blockIdx.y;
    int i = blockIdx.x*256 + threadIdx.x;
    if (i >= NN) return;
    int incl = rowptr[m*(NN+1) + 1 + i] + boff[m*NB + blockIdx.x];
    rowptr[m*(NN+1) + 1 + i] = incl;
    cursor[m*NN + i] = incl - cnt[m*NN + i];
    if (i == 0 && blockIdx.x == 0) rowptr[m*(NN+1)] = 0;
}

__global__ __launch_bounds__(256) void scatter_kernel(const int* __restrict__ edges, int* __restrict__ cursor,
                                                      int* __restrict__ csr_src, int* __restrict__ csr_dst) {
    int idx = blockIdx.x*256 + threadIdx.x;
    if (idx >= MM*EE) return;
    int m = idx / EE, e = idx - m*EE;
    int src = edges[m*2*EE + e];
    int dst = edges[(m*2+1)*EE + e];
    int pos = atomicAdd(&cursor[m*NN + dst], 1);
    csr_src[m*EE + pos] = src;
    csr_dst[m*EE + pos] = dst;
}

// ---------------- MFMA GEMM + el/er epilogue ----------------
// A [Mrows][256] bf16 row-major; Bt [256][256] bf16 (out-col major: Bt[n][k]=B[k][n])
// C [Mrows][256] bf16. Block = 4 waves: (rowgrp 0/1) x (colhalf 0/1); 32 rows/block.
// a-frag: lane reads A[r0+(lane&15)][k0+(lane>>4)*8 ..+8]; b-frag same pattern on Bt.
// D: col = lane&15, row = (lane>>4)*4 + reg  (m91-verified mapping).
template<int H>
__global__ __launch_bounds__(256) void gemm_mfma_kernel(const unsigned short* __restrict__ A,
                                                        const unsigned short* __restrict__ Bt,
                                                        const float* __restrict__ attl, const float* __restrict__ attr,
                                                        unsigned short* __restrict__ C,
                                                        float* __restrict__ el, float* __restrict__ er) {
    int tid = threadIdx.x;
    int w = tid >> 6, lane = tid & 63;
    int rowgrp = w & 1, half = w >> 1;
    int r0 = blockIdx.x*32 + rowgrp*16;
    int colbase = half * 128;
    int lrow = lane & 15, lk = lane >> 4;

    bf16x8 a[8];
    const unsigned short* ap = A + (size_t)(r0 + lrow)*256 + lk*8;
    #pragma unroll
    for (int k = 0; k < 8; ++k) a[k] = *(const bf16x8*)(ap + k*32);

    float pelv[2][4] = {{0.f,0.f,0.f,0.f},{0.f,0.f,0.f,0.f}};
    float perv[2][4] = {{0.f,0.f,0.f,0.f},{0.f,0.f,0.f,0.f}};

    #pragma unroll
    for (int n = 0; n < 8; ++n) {
        int col0 = colbase + n*16;
        const unsigned short* bp = Bt + (size_t)(col0 + lrow)*256 + lk*8;
        f32x4 acc = {0.f, 0.f, 0.f, 0.f};
        #pragma unroll
        for (int k = 0; k < 8; ++k) {
            bf16x8 bfr = *(const bf16x8*)(bp + k*32);
            acc = __builtin_amdgcn_mfma_f32_16x16x32_bf16(a[k], bfr, acc, 0, 0, 0);
        }
        int col = col0 + lrow;
        float al = attl[col], ar = attr[col];
        int hl = (H == 4) ? (n >> 2) : 0;
        #pragma unroll
        for (int r = 0; r < 4; ++r) {
            float cv = acc[r];
            pelv[hl][r] += cv * al;
            perv[hl][r] += cv * ar;
            C[(size_t)(r0 + lk*4 + r)*256 + col] = f2bf(cv);
        }
    }

    int nhl = (H == 4) ? 2 : 1;
    #pragma unroll
    for (int hl = 0; hl < 2; ++hl) {
        if (hl >= nhl) break;
        #pragma unroll
        for (int r = 0; r < 4; ++r) {
            float pe = pelv[hl][r], pr = perv[hl][r];
            #pragma unroll
            for (int o = 1; o < 16; o <<= 1) { pe += __shfl_xor(pe, o); pr += __shfl_xor(pr, o); }
            pelv[hl][r] = pe; perv[hl][r] = pr;
        }
    }

    if (H == 4) {
        // each (row, head) owned by exactly one wave -> plain stores
        if (lrow == 0) {
            int row = r0 + lk*4;
            #pragma unroll
            for (int hl = 0; hl < 2; ++hl) {
                int head = half*2 + hl;
                #pragma unroll
                for (int r = 0; r < 4; ++r) {
                    el[(size_t)(row + r)*4 + head] = pelv[hl][r];
                    er[(size_t)(row + r)*4 + head] = perv[hl][r];
                }
            }
        }
    } else {
        __shared__ float elds[2][32], erds[2][32];
        if (lrow == 0) {
            int rib = rowgrp*16 + lk*4;
            #pragma unroll
            for (int r = 0; r < 4; ++r) {
                elds[half][rib + r] = pelv[0][r];
                erds[half][rib + r] = perv[0][r];
            }
        }
        __syncthreads();
        if (tid < 32) {
            el[blockIdx.x*32 + tid] = elds[0][tid] + elds[1][tid];
            er[blockIdx.x*32 + tid] = erds[0][tid] + erds[1][tid];
        }
    }
}

// ---------------- edge coefficients ee = exp(leakyrelu(el[src]+er[dst])) ----------------
template<int H>
__global__ __launch_bounds__(256) void edge_ee_kernel(const int* __restrict__ csr_src, const int* __restrict__ csr_dst,
                                                      const float* __restrict__ el, const float* __restrict__ er,
                                                      float* __restrict__ ee) {
    int idx = blockIdx.x*256 + threadIdx.x;
    if (idx >= MM*EE) return;
    int src = csr_src[idx], dst = csr_dst[idx];
    if (H == 4) {
        float4 l = *(const float4*)&el[src*4];
        float4 r = *(const float4*)&er[dst*4];
        float4 s;
        s.x = expf(lrelu(l.x + r.x));
        s.y = expf(lrelu(l.y + r.y));
        s.z = expf(lrelu(l.z + r.z));
        s.w = expf(lrelu(l.w + r.w));
        *(float4*)&ee[(size_t)idx*4] = s;
    } else {
        ee[idx] = expf(lrelu(el[src] + er[dst]));
    }
}

// ---------------- per-dst aggregation ----------------
// One wave per (node, metapath); block = 4 waves = 4 consecutive nodes.
// 2 edge-slots of 32 lanes; lane covers 8 feats (16B load); bf16 z output.
template<int H, bool RELU>
__global__ __launch_bounds__(256) void agg_kernel(const unsigned short* __restrict__ feat,
                                                  const float* __restrict__ ee,
                                                  const int* __restrict__ rowptr,
                                                  const int* __restrict__ csr_src,
                                                  unsigned short* __restrict__ z) {
    int m = blockIdx.y;
    int tid = threadIdx.x;
    int lane = tid & 63, wv = tid >> 6;
    int n = blockIdx.x * 4 + wv;
    int eslot = lane >> 5, flane = lane & 31;
    int h = (H == 4) ? (flane >> 3) : 0;
    int beg = rowptr[m*(NN+1) + n], end = rowptr[m*(NN+1) + n + 1];
    const int eb = m*EE;

    float a[8] = {};
    float den = 0.f;
    int e0 = beg + eslot;

    int   sA = 0, sB = 0;
    float wA = 0.f, wB = 0.f;
    if (e0 < end)     { sA = csr_src[eb+e0];   wA = (H==4)? ee[(size_t)(eb+e0  )*4+h] : ee[eb+e0  ]; }
    if (e0 + 2 < end) { sB = csr_src[eb+e0+2]; wB = (H==4)? ee[(size_t)(eb+e0+2)*4+h] : ee[eb+e0+2]; }

    for (int e = e0; e < end; e += 2) {
        uint4 v = *(const uint4*)(feat + (size_t)sA*256 + flane*8);
        float w = wA;
        sA = sB; wA = wB;
        if (e + 4 < end) {
            sB = csr_src[eb+e+4];
            wB = (H==4)? ee[(size_t)(eb+e+4)*4+h] : ee[eb+e+4];
        }
        den += w;
        a[0] += w * bflo(v.x); a[1] += w * bfhi(v.x);
        a[2] += w * bflo(v.y); a[3] += w * bfhi(v.y);
        a[4] += w * bflo(v.z); a[5] += w * bfhi(v.z);
        a[6] += w * bflo(v.w); a[7] += w * bfhi(v.w);
    }

    #pragma unroll
    for (int j = 0; j < 8; ++j) a[j] += __shfl_xor(a[j], 32);
    den += __shfl_xor(den, 32);

    if (eslot == 0) {
        float inv = 1.f / (den + 1e-9f);
        #pragma unroll
        for (int j = 0; j < 8; ++j) {
            a[j] *= inv;
            if (RELU) a[j] = fmaxf(a[j], 0.f);
        }
        uint4 pk;
        pk.x = pk2bf(a[0], a[1]);
        pk.y = pk2bf(a[2], a[3]);
        pk.z = pk2bf(a[4], a[5]);
        pk.w = pk2bf(a[6], a[7]);
        *(uint4*)&z[((size_t)n*MM + m)*256 + flane*8] = pk;
    }
}

// ---------------- semantic attention (MFMA): wsum[m] += sum_n tanh(z@W+b)·v ----------------
// Z [NN*MM][256] bf16; Wt [128][256] bf16. Block = 4 waves x 16 rows = 64 rows.
__global__ __launch_bounds__(256) void semw_mfma_kernel(const unsigned short* __restrict__ Z,
                                                        const unsigned short* __restrict__ Wt,
                                                        const float* __restrict__ bias, const float* __restrict__ v,
                                                        float* __restrict__ wsum) {
    int tid = threadIdx.x;
    int w = tid >> 6, lane = tid & 63;
    int r0 = blockIdx.x*64 + w*16;
    int lrow = lane & 15, lk = lane >> 4;

    int arow = r0 + lrow;
    if (arow >= NN*MM) arow = NN*MM - 1;   // clamp; masked in epilogue
    bf16x8 a[8];
    const unsigned short* ap = Z + (size_t)arow*256 + lk*8;
    #pragma unroll
    for (int k = 0; k < 8; ++k) a[k] = *(const bf16x8*)(ap + k*32);

    float p[4] = {0.f, 0.f, 0.f, 0.f};
    #pragma unroll
    for (int n = 0; n < 8; ++n) {
        int col = n*16 + lrow;
        const unsigned short* bp = Wt + (size_t)col*256 + lk*8;
        f32x4 acc = {0.f, 0.f, 0.f, 0.f};
        #pragma unroll
        for (int k = 0; k < 8; ++k) {
            bf16x8 bfr = *(const bf16x8*)(bp + k*32);
            acc = __builtin_amdgcn_mfma_f32_16x16x32_bf16(a[k], bfr, acc, 0, 0, 0);
        }
        float bb = bias[col], vv = v[col];
        #pragma unroll
        for (int r = 0; r < 4; ++r)
            p[r] += tanhf(acc[r] + bb) * vv;
    }

    #pragma unroll
    for (int r = 0; r < 4; ++r) {
        #pragma unroll
        for (int o = 1; o < 16; o <<= 1) p[r] += __shfl_xor(p[r], o);
    }

    __shared__ float loc[3];
    if (tid < 3) loc[tid] = 0.f;
    __syncthreads();
    if (lrow == 0) {
        #pragma unroll
        for (int r = 0; r < 4; ++r) {
            int row = r0 + lk*4 + r;
            if (row < NN*MM) atomicAdd(&loc[row % MM], p[r]);
        }
    }
    __syncthreads();
    if (tid < 3) atomicAdd(&wsum[tid], loc[tid]);
}

__global__ void beta_kernel(const float* __restrict__ wsum, float* __restrict__ beta, float* att_out) {
    if (threadIdx.x == 0 && blockIdx.x == 0) {
        float w0 = wsum[0] / (float)NN, w1 = wsum[1] / (float)NN, w2 = wsum[2] / (float)NN;
        float mx = fmaxf(w0, fmaxf(w1, w2));
        float e0 = expf(w0 - mx), e1 = expf(w1 - mx), e2 = expf(w2 - mx);
        float s = e0 + e1 + e2;
        beta[0] = e0 / s; beta[1] = e1 / s; beta[2] = e2 / s;
        if (att_out) { att_out[0] = e0/s; att_out[1] = e1/s; att_out[2] = e2/s; }
    }
}

// layer-1 combine: z (bf16) -> h (bf16)
__global__ __launch_bounds__(128) void combine_bf16_kernel(const unsigned short* __restrict__ z, const float* __restrict__ beta,
                                                           unsigned short* __restrict__ outb) {
    int n = blockIdx.x, t = threadIdx.x;
    float b0 = beta[0], b1 = beta[1], b2 = beta[2];
    size_t base = (size_t)n*MM*256 + t*2;
    unsigned z0 = *(const unsigned*)&z[base];
    unsigned z1 = *(const unsigned*)&z[base + 256];
    unsigned z2 = *(const unsigned*)&z[base + 512];
    float ox = b0*bflo(z0) + b1*bflo(z1) + b2*bflo(z2);
    float oy = b0*bfhi(z0) + b1*bfhi(z1) + b2*bfhi(z2);
    *(unsigned*)&outb[(size_t)n*256 + t*2] = pk2bf(ox, oy);
}

// layer-2 combine: z (bf16) -> out (fp32)
__global__ __launch_bounds__(128) void combine_kernel(const unsigned short* __restrict__ z, const float* __restrict__ beta,
                                                      float* __restrict__ out) {
    int n = blockIdx.x, t = threadIdx.x;
    float b0 = beta[0], b1 = beta[1], b2 = beta[2];
    size_t base = (size_t)n*MM*256 + t*2;
    unsigned z0 = *(const unsigned*)&z[base];
    unsigned z1 = *(const unsigned*)&z[base + 256];
    unsigned z2 = *(const unsigned*)&z[base + 512];
    float2 o;
    o.x = b0*bflo(z0) + b1*bflo(z1) + b2*bflo(z2);
    o.y = b0*bfhi(z0) + b1*bfhi(z1) + b2*bfhi(z2);
    *(float2*)&out[(size_t)n*256 + t*2] = o;
}

extern "C" void kernel_launch(void* const* d_in, const int* in_sizes, int n_in,
                              void* d_out, int out_size, void* d_ws, size_t ws_size,
                              hipStream_t stream) {
    const float* x    = (const float*)d_in[0];
    const int*   edges= (const int*)  d_in[1];
    const float* W1   = (const float*)d_in[2];
    const float* al1  = (const float*)d_in[3];
    const float* ar1  = (const float*)d_in[4];
    const float* saW1 = (const float*)d_in[5];
    const float* sab1 = (const float*)d_in[6];
    const float* sav1 = (const float*)d_in[7];
    const float* W2   = (const float*)d_in[8];
    const float* al2  = (const float*)d_in[9];
    const float* ar2  = (const float*)d_in[10];
    const float* saW2 = (const float*)d_in[11];
    const float* sab2 = (const float*)d_in[12];
    const float* sav2 = (const float*)d_in[13];
    float* out = (float*)d_out;

    char* ws = (char*)d_ws;
    size_t off = 0;
    auto alloc = [&](size_t bytes) { void* p = ws + off; off += (bytes + 255) & ~(size_t)255; return p; };
    unsigned short* feat  = (unsigned short*)alloc((size_t)NN*256*2);      // bf16
    unsigned short* z     = (unsigned short*)alloc((size_t)NN*MM*256*2);   // bf16
    unsigned short* xb    = (unsigned short*)alloc((size_t)NN*256*2);      // bf16 x  (reused as hb)
    unsigned short* W1t   = (unsigned short*)alloc(256*256*2);
    unsigned short* saW1t = (unsigned short*)alloc(SAH*256*2);
    unsigned short* W2t   = (unsigned short*)alloc(256*256*2);
    unsigned short* saW2t = (unsigned short*)alloc(SAH*256*2);
    float* ee     = (float*)alloc((size_t)MM*EE*4*4);
    float* el     = (float*)alloc(NN*4*4);
    float* er     = (float*)alloc(NN*4*4);
    float* wsum   = (float*)alloc(256);
    float* beta   = (float*)alloc(256);
    int*   cnt    = (int*)alloc(MM*NN*4);
    int*   cursor = (int*)alloc(MM*NN*4);
    int*   rowptr = (int*)alloc(MM*(NN+1)*4);
    int*   csr_s  = (int*)alloc((size_t)MM*EE*4);
    int*   csr_d  = (int*)alloc((size_t)MM*EE*4);
    int*   bsum   = (int*)alloc(MM*NB*4);
    int*   boff   = (int*)alloc(MM*NB*4);
    unsigned short* hb = xb;   // layer-1 output (bf16), reuses xb space (xb dead after layer-1 GEMM)

    int egrid = (MM*EE + 255)/256;
    dim3 sg(NB, MM);

    // prep: x->bf16, weights -> transposed bf16
    prep_kernel<<<XBLK + 768, 256, 0, stream>>>(x, xb, W1, W1t, saW1, saW1t, W2, W2t, saW2, saW2t);

    // CSR build (shared by both layers)
    hipMemsetAsync(cnt, 0, MM*NN*4, stream);
    hist_kernel<<<egrid, 256, 0, stream>>>(edges, cnt);
    scanA_kernel<<<sg, 256, 0, stream>>>(cnt, rowptr, bsum);
    scanB_kernel<<<1, 128, 0, stream>>>(bsum, boff);
    scanC_kernel<<<sg, 256, 0, stream>>>(cnt, rowptr, boff, cursor);
    scatter_kernel<<<egrid, 256, 0, stream>>>(edges, cursor, csr_s, csr_d);

    // ---- layer 1 ----
    gemm_mfma_kernel<4><<<NN/32, 256, 0, stream>>>(xb, W1t, al1, ar1, feat, el, er);
    edge_ee_kernel<4><<<egrid, 256, 0, stream>>>(csr_s, csr_d, el, er, ee);
    agg_kernel<4, true><<<dim3(NN/4, MM), 256, 0, stream>>>(feat, ee, rowptr, csr_s, z);
    hipMemsetAsync(wsum, 0, 16, stream);
    semw_mfma_kernel<<<(NN*MM + 63)/64, 256, 0, stream>>>(z, saW1t, sab1, sav1, wsum);
    beta_kernel<<<1, 64, 0, stream>>>(wsum, beta, nullptr);
    combine_bf16_kernel<<<NN, 128, 0, stream>>>(z, beta, hb);

    // ---- layer 2 ----
    gemm_mfma_kernel<1><<<NN/32, 256, 0, stream>>>(hb, W2t, al2, ar2, feat, el, er);
    edge_ee_kernel<1><<<egrid, 256, 0, stream>>>(csr_s, csr_d, el, er, ee);
    agg_kernel<1, false><<<dim3(NN/4, MM), 256, 0, stream>>>(feat, ee, rowptr, csr_s, z);
    hipMemsetAsync(wsum, 0, 16, stream);
    semw_mfma_kernel<<<(NN*MM + 63)/64, 256, 0, stream>>>(z, saW2t, sab2, sav2, wsum);
    beta_kernel<<<1, 64, 0, stream>>>(wsum, beta, out + (size_t)NN*256);
    combine_kernel<<<NN, 128, 0, stream>>>(z, beta, out);
}

// Round 7
// 402.533 us; speedup vs baseline: 3.6604x; 1.0349x over previous
//
#include <hip/hip_runtime.h>
#include <hip/hip_bf16.h>
#include <math.h>

#define NN 20000
#define EE 320000
#define MM 3
#define FW 256        // NH*HID = NHO*OUT = 256
#define SAH 128
#define NB 79         // ceil(NN/256)

typedef __attribute__((ext_vector_type(8))) short bf16x8;
typedef __attribute__((ext_vector_type(4))) float f32x4;

static __device__ __forceinline__ float lrelu(float x){ return x > 0.f ? x : 0.2f*x; }

// fp32 -> bf16 round-to-nearest-even
static __device__ __forceinline__ unsigned short f2bf(float f) {
    unsigned u = __float_as_uint(f);
    return (unsigned short)((u + 0x7FFFu + ((u >> 16) & 1u)) >> 16);
}
static __device__ __forceinline__ float bflo(unsigned u){ return __uint_as_float(u << 16); }
static __device__ __forceinline__ float bfhi(unsigned u){ return __uint_as_float(u & 0xffff0000u); }
static __device__ __forceinline__ unsigned pk2bf(float lo, float hi) {
    return ((unsigned)f2bf(lo)) | (((unsigned)f2bf(hi)) << 16);
}

// ---------------- prep: x -> bf16; W1/saW1/W2/saW2 -> transposed bf16 [out][k] ----------------
#define XBLK 2500   // 2500*256 threads * 8 elems = 5.12M = NN*256
__global__ __launch_bounds__(256) void prep_kernel(const float* __restrict__ x, unsigned short* __restrict__ xb,
                                                   const float* __restrict__ W1, unsigned short* __restrict__ W1t,
                                                   const float* __restrict__ saW1, unsigned short* __restrict__ saW1t,
                                                   const float* __restrict__ W2, unsigned short* __restrict__ W2t,
                                                   const float* __restrict__ saW2, unsigned short* __restrict__ saW2t) {
    int b = blockIdx.x, tid = threadIdx.x;
    if (b < XBLK) {
        int i = b*256 + tid;           // uint4 index, 8 elems each
        const float4* p = (const float4*)x + (size_t)i*2;
        float4 v0 = p[0], v1 = p[1];
        uint4 o;
        o.x = pk2bf(v0.x, v0.y); o.y = pk2bf(v0.z, v0.w);
        o.z = pk2bf(v1.x, v1.y); o.w = pk2bf(v1.z, v1.w);
        ((uint4*)xb)[i] = o;
        return;
    }
    int b2 = b - XBLK;
    if (b2 < 256)      { int n = b2;       W1t  [(size_t)n*256 + tid] = f2bf(W1  [(size_t)tid*256 + n]); }
    else if (b2 < 384) { int n = b2 - 256; saW1t[(size_t)n*256 + tid] = f2bf(saW1[(size_t)tid*SAH + n]); }
    else if (b2 < 640) { int n = b2 - 384; W2t  [(size_t)n*256 + tid] = f2bf(W2  [(size_t)tid*256 + n]); }
    else               { int n = b2 - 640; saW2t[(size_t)n*256 + tid] = f2bf(saW2[(size_t)tid*SAH + n]); }
}

// ---------------- CSR build ----------------
// 4 edges per thread (int4 loads)
__global__ __launch_bounds__(256) void hist_kernel(const int* __restrict__ edges, int* __restrict__ cnt) {
    int idx = blockIdx.x*256 + threadIdx.x;
    if (idx >= MM*EE/4) return;
    int m = idx / (EE/4), e4 = idx - m*(EE/4);
    int4 d = ((const int4*)(edges + (size_t)(m*2+1)*EE))[e4];
    atomicAdd(&cnt[m*NN + d.x], 1);
    atomicAdd(&cnt[m*NN + d.y], 1);
    atomicAdd(&cnt[m*NN + d.z], 1);
    atomicAdd(&cnt[m*NN + d.w], 1);
}

__global__ __launch_bounds__(256) void scanA_kernel(const int* __restrict__ cnt, int* __restrict__ rowptr, int* __restrict__ bsum) {
    int m = blockIdx.y;
    int i = blockIdx.x*256 + threadIdx.x;
    int v = (i < NN) ? cnt[m*NN + i] : 0;
    int lane = threadIdx.x & 63;
    int val = v;
    #pragma unroll
    for (int o = 1; o < 64; o <<= 1) { int t = __shfl_up(val, o); if (lane >= o) val += t; }
    __shared__ int ws[4];
    int w = threadIdx.x >> 6;
    if (lane == 63) ws[w] = val;
    __syncthreads();
    #pragma unroll
    for (int j = 0; j < 3; ++j) if (j < w) val += ws[j];
    if (i < NN) rowptr[m*(NN+1) + 1 + i] = val;
    if (threadIdx.x == 255) bsum[m*NB + blockIdx.x] = val;
}

__global__ __launch_bounds__(128) void scanB_kernel(const int* __restrict__ bsum, int* __restrict__ boff) {
    __shared__ int s[128];
    int t = threadIdx.x;
    for (int m = 0; m < MM; ++m) {
        int v = (t < NB) ? bsum[m*NB + t] : 0;
        s[t] = v; __syncthreads();
        for (int o = 1; o < 128; o <<= 1) {
            int x = (t >= o) ? s[t - o] : 0;
            __syncthreads();
            s[t] += x;
            __syncthreads();
        }
        if (t < NB) boff[m*NB + t] = s[t] - v;   // exclusive
        __syncthreads();
    }
}

__global__ __launch_bounds__(256) void scanC_kernel(const int* __restrict__ cnt, int* __restrict__ rowptr,
                                                    const int* __restrict__ boff, int* __restrict__ cursor) {
    int m = blockIdx.y;
    int i = blockIdx.x*256 + threadIdx.x;
    if (i >= NN) return;
    int incl = rowptr[m*(NN+1) + 1 + i] + boff[m*NB + blockIdx.x];
    rowptr[m*(NN+1) + 1 + i] = incl;
    cursor[m*NN + i] = incl - cnt[m*NN + i];
    if (i == 0 && blockIdx.x == 0) rowptr[m*(NN+1)] = 0;
}

// packed (src,dst) CSR: ONE 8B store per edge (halves random-write line touches)
__global__ __launch_bounds__(256) void scatter_kernel(const int* __restrict__ edges, int* __restrict__ cursor,
                                                      uint2* __restrict__ csr) {
    int idx = blockIdx.x*256 + threadIdx.x;
    if (idx >= MM*EE/4) return;
    int m = idx / (EE/4), e4 = idx - m*(EE/4);
    int4 s = ((const int4*)(edges + (size_t)(m*2  )*EE))[e4];
    int4 d = ((const int4*)(edges + (size_t)(m*2+1)*EE))[e4];
    int p0 = atomicAdd(&cursor[m*NN + d.x], 1); csr[(size_t)m*EE + p0] = make_uint2((unsigned)s.x, (unsigned)d.x);
    int p1 = atomicAdd(&cursor[m*NN + d.y], 1); csr[(size_t)m*EE + p1] = make_uint2((unsigned)s.y, (unsigned)d.y);
    int p2 = atomicAdd(&cursor[m*NN + d.z], 1); csr[(size_t)m*EE + p2] = make_uint2((unsigned)s.z, (unsigned)d.z);
    int p3 = atomicAdd(&cursor[m*NN + d.w], 1); csr[(size_t)m*EE + p3] = make_uint2((unsigned)s.w, (unsigned)d.w);
}

// ---------------- MFMA GEMM + el/er epilogue ----------------
template<int H>
__global__ __launch_bounds__(256) void gemm_mfma_kernel(const unsigned short* __restrict__ A,
                                                        const unsigned short* __restrict__ Bt,
                                                        const float* __restrict__ attl, const float* __restrict__ attr,
                                                        unsigned short* __restrict__ C,
                                                        float* __restrict__ el, float* __restrict__ er) {
    int tid = threadIdx.x;
    int w = tid >> 6, lane = tid & 63;
    int rowgrp = w & 1, half = w >> 1;
    int r0 = blockIdx.x*32 + rowgrp*16;
    int colbase = half * 128;
    int lrow = lane & 15, lk = lane >> 4;

    bf16x8 a[8];
    const unsigned short* ap = A + (size_t)(r0 + lrow)*256 + lk*8;
    #pragma unroll
    for (int k = 0; k < 8; ++k) a[k] = *(const bf16x8*)(ap + k*32);

    float pelv[2][4] = {{0.f,0.f,0.f,0.f},{0.f,0.f,0.f,0.f}};
    float perv[2][4] = {{0.f,0.f,0.f,0.f},{0.f,0.f,0.f,0.f}};

    #pragma unroll
    for (int n = 0; n < 8; ++n) {
        int col0 = colbase + n*16;
        const unsigned short* bp = Bt + (size_t)(col0 + lrow)*256 + lk*8;
        f32x4 acc = {0.f, 0.f, 0.f, 0.f};
        #pragma unroll
        for (int k = 0; k < 8; ++k) {
            bf16x8 bfr = *(const bf16x8*)(bp + k*32);
            acc = __builtin_amdgcn_mfma_f32_16x16x32_bf16(a[k], bfr, acc, 0, 0, 0);
        }
        int col = col0 + lrow;
        float al = attl[col], ar = attr[col];
        int hl = (H == 4) ? (n >> 2) : 0;
        #pragma unroll
        for (int r = 0; r < 4; ++r) {
            float cv = acc[r];
            pelv[hl][r] += cv * al;
            perv[hl][r] += cv * ar;
            C[(size_t)(r0 + lk*4 + r)*256 + col] = f2bf(cv);
        }
    }

    int nhl = (H == 4) ? 2 : 1;
    #pragma unroll
    for (int hl = 0; hl < 2; ++hl) {
        if (hl >= nhl) break;
        #pragma unroll
        for (int r = 0; r < 4; ++r) {
            float pe = pelv[hl][r], pr = perv[hl][r];
            #pragma unroll
            for (int o = 1; o < 16; o <<= 1) { pe += __shfl_xor(pe, o); pr += __shfl_xor(pr, o); }
            pelv[hl][r] = pe; perv[hl][r] = pr;
        }
    }

    if (H == 4) {
        if (lrow == 0) {
            int row = r0 + lk*4;
            #pragma unroll
            for (int hl = 0; hl < 2; ++hl) {
                int head = half*2 + hl;
                #pragma unroll
                for (int r = 0; r < 4; ++r) {
                    el[(size_t)(row + r)*4 + head] = pelv[hl][r];
                    er[(size_t)(row + r)*4 + head] = perv[hl][r];
                }
            }
        }
    } else {
        __shared__ float elds[2][32], erds[2][32];
        if (lrow == 0) {
            int rib = rowgrp*16 + lk*4;
            #pragma unroll
            for (int r = 0; r < 4; ++r) {
                elds[half][rib + r] = pelv[0][r];
                erds[half][rib + r] = perv[0][r];
            }
        }
        __syncthreads();
        if (tid < 32) {
            el[blockIdx.x*32 + tid] = elds[0][tid] + elds[1][tid];
            er[blockIdx.x*32 + tid] = erds[0][tid] + erds[1][tid];
        }
    }
}

// ---------------- edge coefficients ee = exp(leakyrelu(el[src]+er[dst])) ----------------
template<int H>
__global__ __launch_bounds__(256) void edge_ee_kernel(const uint2* __restrict__ csr,
                                                      const float* __restrict__ el, const float* __restrict__ er,
                                                      float* __restrict__ ee) {
    int idx = blockIdx.x*256 + threadIdx.x;
    if (idx >= MM*EE) return;
    uint2 sd = csr[idx];
    int src = sd.x, dst = sd.y;
    if (H == 4) {
        float4 l = *(const float4*)&el[src*4];
        float4 r = *(const float4*)&er[dst*4];
        float4 s;
        s.x = expf(lrelu(l.x + r.x));
        s.y = expf(lrelu(l.y + r.y));
        s.z = expf(lrelu(l.z + r.z));
        s.w = expf(lrelu(l.w + r.w));
        *(float4*)&ee[(size_t)idx*4] = s;
    } else {
        ee[idx] = expf(lrelu(el[src] + er[dst]));
    }
}

// ---------------- per-dst aggregation ----------------
// One wave per (node, metapath); block = 4 waves = 4 consecutive nodes.
// 2 edge-slots of 32 lanes; lane covers 8 feats (16B load); bf16 z output.
template<int H, bool RELU>
__global__ __launch_bounds__(256) void agg_kernel(const unsigned short* __restrict__ feat,
                                                  const float* __restrict__ ee,
                                                  const int* __restrict__ rowptr,
                                                  const uint2* __restrict__ csr,
                                                  unsigned short* __restrict__ z) {
    int m = blockIdx.y;
    int tid = threadIdx.x;
    int lane = tid & 63, wv = tid >> 6;
    int n = blockIdx.x * 4 + wv;
    int eslot = lane >> 5, flane = lane & 31;
    int h = (H == 4) ? (flane >> 3) : 0;
    int beg = rowptr[m*(NN+1) + n], end = rowptr[m*(NN+1) + n + 1];
    const int eb = m*EE;

    float a[8] = {};
    float den = 0.f;
    int e0 = beg + eslot;

    int   sA = 0, sB = 0;
    float wA = 0.f, wB = 0.f;
    if (e0 < end)     { sA = csr[(size_t)eb+e0  ].x; wA = (H==4)? ee[(size_t)(eb+e0  )*4+h] : ee[eb+e0  ]; }
    if (e0 + 2 < end) { sB = csr[(size_t)eb+e0+2].x; wB = (H==4)? ee[(size_t)(eb+e0+2)*4+h] : ee[eb+e0+2]; }

    for (int e = e0; e < end; e += 2) {
        uint4 v = *(const uint4*)(feat + (size_t)sA*256 + flane*8);
        float w = wA;
        sA = sB; wA = wB;
        if (e + 4 < end) {
            sB = csr[(size_t)eb+e+4].x;
            wB = (H==4)? ee[(size_t)(eb+e+4)*4+h] : ee[eb+e+4];
        }
        den += w;
        a[0] += w * bflo(v.x); a[1] += w * bfhi(v.x);
        a[2] += w * bflo(v.y); a[3] += w * bfhi(v.y);
        a[4] += w * bflo(v.z); a[5] += w * bfhi(v.z);
        a[6] += w * bflo(v.w); a[7] += w * bfhi(v.w);
    }

    #pragma unroll
    for (int j = 0; j < 8; ++j) a[j] += __shfl_xor(a[j], 32);
    den += __shfl_xor(den, 32);

    if (eslot == 0) {
        float inv = 1.f / (den + 1e-9f);
        #pragma unroll
        for (int j = 0; j < 8; ++j) {
            a[j] *= inv;
            if (RELU) a[j] = fmaxf(a[j], 0.f);
        }
        uint4 pk;
        pk.x = pk2bf(a[0], a[1]);
        pk.y = pk2bf(a[2], a[3]);
        pk.z = pk2bf(a[4], a[5]);
        pk.w = pk2bf(a[6], a[7]);
        *(uint4*)&z[((size_t)n*MM + m)*256 + flane*8] = pk;
    }
}

// ---------------- semantic attention (MFMA): wsum[m] += sum_n tanh(z@W+b)·v ----------------
__global__ __launch_bounds__(256) void semw_mfma_kernel(const unsigned short* __restrict__ Z,
                                                        const unsigned short* __restrict__ Wt,
                                                        const float* __restrict__ bias, const float* __restrict__ v,
                                                        float* __restrict__ wsum) {
    int tid = threadIdx.x;
    int w = tid >> 6, lane = tid & 63;
    int r0 = blockIdx.x*64 + w*16;
    int lrow = lane & 15, lk = lane >> 4;

    int arow = r0 + lrow;
    if (arow >= NN*MM) arow = NN*MM - 1;   // clamp; masked in epilogue
    bf16x8 a[8];
    const unsigned short* ap = Z + (size_t)arow*256 + lk*8;
    #pragma unroll
    for (int k = 0; k < 8; ++k) a[k] = *(const bf16x8*)(ap + k*32);

    float p[4] = {0.f, 0.f, 0.f, 0.f};
    #pragma unroll
    for (int n = 0; n < 8; ++n) {
        int col = n*16 + lrow;
        const unsigned short* bp = Wt + (size_t)col*256 + lk*8;
        f32x4 acc = {0.f, 0.f, 0.f, 0.f};
        #pragma unroll
        for (int k = 0; k < 8; ++k) {
            bf16x8 bfr = *(const bf16x8*)(bp + k*32);
            acc = __builtin_amdgcn_mfma_f32_16x16x32_bf16(a[k], bfr, acc, 0, 0, 0);
        }
        float bb = bias[col], vv = v[col];
        #pragma unroll
        for (int r = 0; r < 4; ++r)
            p[r] += tanhf(acc[r] + bb) * vv;
    }

    #pragma unroll
    for (int r = 0; r < 4; ++r) {
        #pragma unroll
        for (int o = 1; o < 16; o <<= 1) p[r] += __shfl_xor(p[r], o);
    }

    __shared__ float loc[3];
    if (tid < 3) loc[tid] = 0.f;
    __syncthreads();
    if (lrow == 0) {
        #pragma unroll
        for (int r = 0; r < 4; ++r) {
            int row = r0 + lk*4 + r;
            if (row < NN*MM) atomicAdd(&loc[row % MM], p[r]);
        }
    }
    __syncthreads();
    if (tid < 3) atomicAdd(&wsum[tid], loc[tid]);
}

__global__ void beta_kernel(const float* __restrict__ wsum, float* __restrict__ beta, float* att_out) {
    if (threadIdx.x == 0 && blockIdx.x == 0) {
        float w0 = wsum[0] / (float)NN, w1 = wsum[1] / (float)NN, w2 = wsum[2] / (float)NN;
        float mx = fmaxf(w0, fmaxf(w1, w2));
        float e0 = expf(w0 - mx), e1 = expf(w1 - mx), e2 = expf(w2 - mx);
        float s = e0 + e1 + e2;
        beta[0] = e0 / s; beta[1] = e1 / s; beta[2] = e2 / s;
        if (att_out) { att_out[0] = e0/s; att_out[1] = e1/s; att_out[2] = e2/s; }
    }
}

// layer-1 combine: z (bf16) -> h (bf16)
__global__ __launch_bounds__(128) void combine_bf16_kernel(const unsigned short* __restrict__ z, const float* __restrict__ beta,
                                                           unsigned short* __restrict__ outb) {
    int n = blockIdx.x, t = threadIdx.x;
    float b0 = beta[0], b1 = beta[1], b2 = beta[2];
    size_t base = (size_t)n*MM*256 + t*2;
    unsigned z0 = *(const unsigned*)&z[base];
    unsigned z1 = *(const unsigned*)&z[base + 256];
    unsigned z2 = *(const unsigned*)&z[base + 512];
    float ox = b0*bflo(z0) + b1*bflo(z1) + b2*bflo(z2);
    float oy = b0*bfhi(z0) + b1*bfhi(z1) + b2*bfhi(z2);
    *(unsigned*)&outb[(size_t)n*256 + t*2] = pk2bf(ox, oy);
}

// layer-2 combine: z (bf16) -> out (fp32)
__global__ __launch_bounds__(128) void combine_kernel(const unsigned short* __restrict__ z, const float* __restrict__ beta,
                                                      float* __restrict__ out) {
    int n = blockIdx.x, t = threadIdx.x;
    float b0 = beta[0], b1 = beta[1], b2 = beta[2];
    size_t base = (size_t)n*MM*256 + t*2;
    unsigned z0 = *(const unsigned*)&z[base];
    unsigned z1 = *(const unsigned*)&z[base + 256];
    unsigned z2 = *(const unsigned*)&z[base + 512];
    float2 o;
    o.x = b0*bflo(z0) + b1*bflo(z1) + b2*bflo(z2);
    o.y = b0*bfhi(z0) + b1*bfhi(z1) + b2*bfhi(z2);
    *(float2*)&out[(size_t)n*256 + t*2] = o;
}

extern "C" void kernel_launch(void* const* d_in, const int* in_sizes, int n_in,
                              void* d_out, int out_size, void* d_ws, size_t ws_size,
                              hipStream_t stream) {
    const float* x    = (const float*)d_in[0];
    const int*   edges= (const int*)  d_in[1];
    const float* W1   = (const float*)d_in[2];
    const float* al1  = (const float*)d_in[3];
    const float* ar1  = (const float*)d_in[4];
    const float* saW1 = (const float*)d_in[5];
    const float* sab1 = (const float*)d_in[6];
    const float* sav1 = (const float*)d_in[7];
    const float* W2   = (const float*)d_in[8];
    const float* al2  = (const float*)d_in[9];
    const float* ar2  = (const float*)d_in[10];
    const float* saW2 = (const float*)d_in[11];
    const float* sab2 = (const float*)d_in[12];
    const float* sav2 = (const float*)d_in[13];
    float* out = (float*)d_out;

    char* ws = (char*)d_ws;
    size_t off = 0;
    auto alloc = [&](size_t bytes) { void* p = ws + off; off += (bytes + 255) & ~(size_t)255; return p; };
    unsigned short* feat  = (unsigned short*)alloc((size_t)NN*256*2);      // bf16
    unsigned short* z     = (unsigned short*)alloc((size_t)NN*MM*256*2);   // bf16
    unsigned short* xb    = (unsigned short*)alloc((size_t)NN*256*2);      // bf16 x  (reused as hb)
    unsigned short* W1t   = (unsigned short*)alloc(256*256*2);
    unsigned short* saW1t = (unsigned short*)alloc(SAH*256*2);
    unsigned short* W2t   = (unsigned short*)alloc(256*256*2);
    unsigned short* saW2t = (unsigned short*)alloc(SAH*256*2);
    float* ee     = (float*)alloc((size_t)MM*EE*4*4);
    float* el     = (float*)alloc(NN*4*4);
    float* er     = (float*)alloc(NN*4*4);
    float* wsum   = (float*)alloc(256);
    float* beta   = (float*)alloc(256);
    int*   cnt    = (int*)alloc(MM*NN*4);
    int*   cursor = (int*)alloc(MM*NN*4);
    int*   rowptr = (int*)alloc(MM*(NN+1)*4);
    uint2* csr    = (uint2*)alloc((size_t)MM*EE*8);
    int*   bsum   = (int*)alloc(MM*NB*4);
    int*   boff   = (int*)alloc(MM*NB*4);
    unsigned short* hb = xb;   // layer-1 output (bf16), reuses xb space

    int egrid = (MM*EE + 255)/256;
    int egrid4 = (MM*EE/4 + 255)/256;
    dim3 sg(NB, MM);

    // prep: x->bf16, weights -> transposed bf16
    prep_kernel<<<XBLK + 768, 256, 0, stream>>>(x, xb, W1, W1t, saW1, saW1t, W2, W2t, saW2, saW2t);

    // CSR build (shared by both layers)
    hipMemsetAsync(cnt, 0, MM*NN*4, stream);
    hist_kernel<<<egrid4, 256, 0, stream>>>(edges, cnt);
    scanA_kernel<<<sg, 256, 0, stream>>>(cnt, rowptr, bsum);
    scanB_kernel<<<1, 128, 0, stream>>>(bsum, boff);
    scanC_kernel<<<sg, 256, 0, stream>>>(cnt, rowptr, boff, cursor);
    scatter_kernel<<<egrid4, 256, 0, stream>>>(edges, cursor, csr);

    // ---- layer 1 ----
    gemm_mfma_kernel<4><<<NN/32, 256, 0, stream>>>(xb, W1t, al1, ar1, feat, el, er);
    edge_ee_kernel<4><<<egrid, 256, 0, stream>>>(csr, el, er, ee);
    agg_kernel<4, true><<<dim3(NN/4, MM), 256, 0, stream>>>(feat, ee, rowptr, csr, z);
    hipMemsetAsync(wsum, 0, 16, stream);
    semw_mfma_kernel<<<(NN*MM + 63)/64, 256, 0, stream>>>(z, saW1t, sab1, sav1, wsum);
    beta_kernel<<<1, 64, 0, stream>>>(wsum, beta, nullptr);
    combine_bf16_kernel<<<NN, 128, 0, stream>>>(z, beta, hb);

    // ---- layer 2 ----
    gemm_mfma_kernel<1><<<NN/32, 256, 0, stream>>>(hb, W2t, al2, ar2, feat, el, er);
    edge_ee_kernel<1><<<egrid, 256, 0, stream>>>(csr, el, er, ee);
    agg_kernel<1, false><<<dim3(NN/4, MM), 256, 0, stream>>>(feat, ee, rowptr, csr, z);
    hipMemsetAsync(wsum, 0, 16, stream);
    semw_mfma_kernel<<<(NN*MM + 63)/64, 256, 0, stream>>>(z, saW2t, sab2, sav2, wsum);
    beta_kernel<<<1, 64, 0, stream>>>(wsum, beta, out + (size_t)NN*256);
    combine_kernel<<<NN, 128, 0, stream>>>(z, beta, out);
}